// Round 25
// baseline (715.394 us; speedup 1.0000x reference)
//
#include <hip/hip_runtime.h>
#include <hip/hip_fp16.h>

// CAPTNet block. B=8, CIN=3, H=W=256, DIM=48, HEADS=4 (ch=12), HID=96.
// Round 25: kA9 -> kA10 with 384-thread blocks. r24's 256-thread tile has
// 324 halo px -> threads 0-67 do DOUBLE staging/conv while 6 of 8 waves
// idle at the barrier, and occupancy is 8 waves/CU. 384 threads: 1 px per
// thread for staging/conv (balanced), and 2 blocks/CU x 6 waves = 12
// waves/CU (3/SIMD) for better latency hiding. dwconv/v/Gram guarded to
// tid<256 / tid<336. k3/k4b/k5b verbatim r24 (667us, absmax 9.77e-4).
// region layout (r7): (b*256+gy)*98304 + chunk*4096 + gx*16, 24 chunks.
//   chunks 18..23: vdw fp16 (kA10 -> k4b); k4b writes y fp16 chunks 0..23.
// s0 (3 fp32) separate float4/pixel array (k4b -> k5b).

#define NPIX 65536
#define ROWB 98304        // bytes per (batch,row): 24 chunks * 4096
#define REGPB 25165824ull // bytes per batch in region
#define HSTRIDE 332       // k5b halo LDS row stride (half2 elems) [r7]
#define HA 324            // kA10 halo LDS row stride (u32/half2 elems)
#define KQP 129           // kA10 q/k LDS row stride in u32 (128 px-pairs + pad)

union F4U { float4 f4; unsigned int u[4]; };

typedef _Float16 h2f __attribute__((ext_vector_type(2)));
union U32H2 { unsigned int u; h2f h; };

__device__ __forceinline__ float2 uh2f(unsigned int u) {
  __half2 h; *(unsigned int*)&h = u; return __half22float2(h);
}
__device__ __forceinline__ unsigned int fpack(float a, float b) {
  __half2 h = __halves2half2(__float2half_rn(a), __float2half_rn(b));
  return *(unsigned int*)&h;
}
__device__ __forceinline__ float fdot2u(unsigned int a, unsigned int b, float c) {
  U32H2 ua, ub; ua.u = a; ub.u = b;
  return __builtin_amdgcn_fdot2(ua.h, ub.h, c, false);
}

// == kA10: 384-thr: in_proj+LN1(analytic)+qkv conv(dot2)+dwconv+Gram+v =====
__global__ __launch_bounds__(384, 2) void kA10(
    const float* __restrict__ x, const float* __restrict__ ipw,
    const float* __restrict__ ipb, const float* __restrict__ lnw,
    const float* __restrict__ lnb, const float* __restrict__ qw,
    const float* __restrict__ qb, const float* __restrict__ dww,
    const float* __restrict__ dwb, char* __restrict__ region,
    float* __restrict__ red) {
  __shared__ unsigned int th[24 * HA];          // LN1 out, ch pairs fp16
  __shared__ unsigned int um[12 * HA];          // conv out 24ch fp16 pairs
  __shared__ unsigned int qsm[24 * KQP];        // q: ch-major, 2px per u32
  __shared__ unsigned int ksm[24 * KQP];        // k: ch-major, 2px per u32
  __shared__ __align__(16) unsigned int wgp[576];  // conv w fp16 pairs [c2][o]
  __shared__ float qbf[24];
  __shared__ unsigned int dwp[72 * 9];          // dw w fp16 ch-pairs
  __shared__ unsigned int dbp[72];
  __shared__ float s_ipw[144], s_ipb[48], s_lnw[48], s_lnb[48];
  __shared__ float s_C[14];   // LN1 analytic scalars
  const int tid = threadIdx.x;
  for (int i = tid; i < 648; i += 384)
    dwp[i] = fpack(dww[(i / 9) * 18 + (i % 9)], dww[(i / 9) * 18 + 9 + (i % 9)]);
  if (tid < 72) dbp[tid] = fpack(dwb[2 * tid], dwb[2 * tid + 1]);
  if (tid < 144) s_ipw[tid] = ipw[tid];
  if (tid < 48) { s_ipb[tid] = ipb[tid]; s_lnw[tid] = lnw[tid]; s_lnb[tid] = lnb[tid]; }
  if (tid >= 192 && tid < 206) {
    const int e = tid - 192;
    float s = 0.f;
    if (e < 3) {
      for (int c = 0; c < 48; ++c) s += ipw[3 * c + e];
    } else if (e == 3) {
      for (int c = 0; c < 48; ++c) s += ipb[c];
    } else if (e < 10) {
      const int k0[6] = {0, 0, 0, 1, 1, 2}, k1[6] = {0, 1, 2, 1, 2, 2};
      const int a = k0[e - 4], bq = k1[e - 4];
      for (int c = 0; c < 48; ++c) s += ipw[3 * c + a] * ipw[3 * c + bq];
    } else if (e < 13) {
      for (int c = 0; c < 48; ++c) s += ipw[3 * c + (e - 10)] * ipb[c];
    } else {
      for (int c = 0; c < 48; ++c) s += ipb[c] * ipb[c];
    }
    s_C[e] = s;
  }
  const int b = blockIdx.x >> 8;
  const int tile = blockIdx.x & 255;
  const int ty0 = (tile >> 4) << 4, tx0 = (tile & 15) << 4;
  const int py = (tid & 255) >> 4, px = tid & 15;   // center px for tid<256
  const int hp = (py + 1) * 18 + (px + 1);
  char* regb = region + (size_t)b * REGPB;
  const int offs[9] = {-19, -18, -17, -1, 0, 1, 17, 18, 19};
  __syncthreads();

  // stage th = LN1(in_proj(x)): ONE pixel per thread (324 <= 384)
  if (tid < 324) {
    const int p = tid;
    const int hy = p / 18, hx = p - hy * 18;
    const int gy = ty0 + hy - 1, gx = tx0 + hx - 1;
    const bool ok = ((unsigned)gy < 256u) && ((unsigned)gx < 256u);
    const int gn = (gy << 8) + gx;
    float x0 = 0.f, x1 = 0.f, x2 = 0.f;
    if (ok) {
      x0 = x[((size_t)b * 3 + 0) * NPIX + gn];
      x1 = x[((size_t)b * 3 + 1) * NPIX + gn];
      x2 = x[((size_t)b * 3 + 2) * NPIX + gn];
    }
    const float mu = (s_C[0]*x0 + s_C[1]*x1 + s_C[2]*x2 + s_C[3]) * (1.f/48.f);
    const float sumsq = s_C[4]*x0*x0 + s_C[7]*x1*x1 + s_C[9]*x2*x2
                      + 2.f*(s_C[5]*x0*x1 + s_C[6]*x0*x2 + s_C[8]*x1*x2
                             + s_C[10]*x0 + s_C[11]*x1 + s_C[12]*x2)
                      + s_C[13];
    const float var = sumsq * (1.f/48.f) - mu * mu;
    const float rs = rsqrtf(var + 1e-6f);
#pragma unroll
    for (int c2 = 0; c2 < 24; ++c2) {
      const float na = s_ipw[6*c2+0]*x0 + s_ipw[6*c2+1]*x1 + s_ipw[6*c2+2]*x2 + s_ipb[2*c2];
      const float nb = s_ipw[6*c2+3]*x0 + s_ipw[6*c2+4]*x1 + s_ipw[6*c2+5]*x2 + s_ipb[2*c2+1];
      th[c2 * HA + p] = fpack((na - mu) * rs * s_lnw[2*c2]   + s_lnb[2*c2],
                              (nb - mu) * rs * s_lnw[2*c2+1] + s_lnb[2*c2+1]);
    }
  }
  __syncthreads();

  auto loadwg = [&](int cb) {
    for (int i = tid; i < 576; i += 384) {
      const int c2 = i / 24, o = i - c2 * 24;
      wgp[i] = fpack(qw[(cb + o) * 48 + 2 * c2], qw[(cb + o) * 48 + 2 * c2 + 1]);
    }
    if (tid < 24) qbf[tid] = qb[cb + tid];
  };
  auto convPhase = [&]() {   // conv 48->24 via dot2, ONE pixel per thread
    if (tid >= 324) return;
    const int p = tid;
    const int hy = p / 18, hx = p - hy * 18;
    const int gy = ty0 + hy - 1, gx = tx0 + hx - 1;
    const bool ok = ((unsigned)gy < 256u) && ((unsigned)gx < 256u);
    float a[24];
#pragma unroll
    for (int j = 0; j < 24; ++j) a[j] = qbf[j];
#pragma unroll 4
    for (int c2 = 0; c2 < 24; ++c2) {
      const unsigned int t = th[c2 * HA + p];
      const uint4* wr = (const uint4*)&wgp[c2 * 24];
#pragma unroll
      for (int k = 0; k < 6; ++k) {
        const uint4 w = wr[k];
        a[4*k+0] = fdot2u(t, w.x, a[4*k+0]);
        a[4*k+1] = fdot2u(t, w.y, a[4*k+1]);
        a[4*k+2] = fdot2u(t, w.z, a[4*k+2]);
        a[4*k+3] = fdot2u(t, w.w, a[4*k+3]);
      }
    }
#pragma unroll
    for (int j = 0; j < 12; ++j)
      um[j * HA + p] = ok ? fpack(a[2 * j], a[2 * j + 1]) : 0u;
  };
  // dwconv 24ch -> ch-major fp16 halves (center 256 px; tid<256)
  auto dwqk = [&](int cpb, unsigned int* dst) {
    if (tid >= 256) return;
    __half* dh = (__half*)dst;
#pragma unroll
    for (int j = 0; j < 12; ++j) {
      const float2 db = uh2f(dbp[cpb + j]);
      float a = db.x, bb = db.y;
      const unsigned int* hrow = &um[j * HA + hp];
      const unsigned int* wp = &dwp[(cpb + j) * 9];
#pragma unroll
      for (int t = 0; t < 9; ++t) {
        const float2 f = uh2f(hrow[offs[t]]);
        const float2 w = uh2f(wp[t]);
        a += w.x * f.x; bb += w.y * f.y;
      }
      dh[(2 * j) * (2 * KQP) + tid]     = __float2half_rn(a);
      dh[(2 * j + 1) * (2 * KQP) + tid] = __float2half_rn(bb);
    }
  };
  auto dwv = [&](int cpb, int chunk0) {
    if (tid >= 256) return;
    unsigned int vp[12];
#pragma unroll
    for (int j = 0; j < 12; ++j) {
      const float2 db = uh2f(dbp[cpb + j]);
      float a = db.x, bb = db.y;
      const unsigned int* hrow = &um[j * HA + hp];
      const unsigned int* wp = &dwp[(cpb + j) * 9];
#pragma unroll
      for (int t = 0; t < 9; ++t) {
        const float2 f = uh2f(hrow[offs[t]]);
        const float2 w = uh2f(wp[t]);
        a += w.x * f.x; bb += w.y * f.y;
      }
      vp[j] = fpack(a, bb);
    }
    char* vrow = regb + (size_t)(ty0 + py) * ROWB + ((tx0 + px) << 4);
#pragma unroll
    for (int q = 0; q < 3; ++q) {
      F4U u;
      u.u[0] = vp[4 * q]; u.u[1] = vp[4 * q + 1];
      u.u[2] = vp[4 * q + 2]; u.u[3] = vp[4 * q + 3];
      *(float4*)(vrow + (chunk0 + q) * 4096) = u.f4;
    }
  };
  // Gram/norms: 1 dot2 per pixel-pair, 4 partial accumulators (tid<336)
  auto gram2 = [&](int hbase) {
    if (tid >= 336) return;
    const int e = tid;
    const int hh = e / 168, r2 = e - hh * 168;
    const unsigned int *ar, *br;
    if (r2 < 144) {
      ar = &qsm[(12 * hh + r2 / 12) * KQP];
      br = &ksm[(12 * hh + r2 % 12) * KQP];
    } else if (r2 < 156) {
      ar = br = &qsm[(12 * hh + (r2 - 144)) * KQP];
    } else {
      ar = br = &ksm[(12 * hh + (r2 - 156)) * KQP];
    }
    float s0 = 0.f, s1 = 0.f, s2 = 0.f, s3 = 0.f;
#pragma unroll 8
    for (int p = 0; p < 128; p += 4) {
      s0 = fdot2u(ar[p],     br[p],     s0);
      s1 = fdot2u(ar[p + 1], br[p + 1], s1);
      s2 = fdot2u(ar[p + 2], br[p + 2], s2);
      s3 = fdot2u(ar[p + 3], br[p + 3], s3);
    }
    atomicAdd(&red[b * 672 + (hbase + hh) * 168 + r2], (s0 + s1) + (s2 + s3));
  };

  loadwg(0);   __syncthreads(); convPhase(); __syncthreads(); dwqk(0, qsm);
  loadwg(48);  __syncthreads(); convPhase(); __syncthreads(); dwqk(24, ksm);
  __syncthreads(); gram2(0);
  loadwg(24);  __syncthreads(); convPhase(); __syncthreads(); dwqk(12, qsm);
  loadwg(72);  __syncthreads(); convPhase(); __syncthreads(); dwqk(36, ksm);
  __syncthreads(); gram2(2);
  loadwg(96);  __syncthreads(); convPhase(); __syncthreads(); dwv(48, 18);
  loadwg(120); __syncthreads(); convPhase(); __syncthreads(); dwv(60, 21);
}

// ================= k3: finalize attn, build fused M [r24 verbatim] ==========
__global__ __launch_bounds__(256) void k3_attn(const float* __restrict__ red,
                                               const float* __restrict__ temp,
                                               const float* __restrict__ aow,
                                               float* __restrict__ Mws) {
  __shared__ float attn[4 * 144];
  const int b = blockIdx.x, tid = threadIdx.x;
  const float* rb = red + b * 672;
  for (int e = tid; e < 576; e += 256) {
    const int h = e / 144, r = e - h * 144;
    const int c = r / 12, d = r - c * 12;
    const float g = rb[h * 168 + r];
    const float nq = fmaxf(sqrtf(rb[h * 168 + 144 + c]), 1e-12f);
    const float nk = fmaxf(sqrtf(rb[h * 168 + 156 + d]), 1e-12f);
    attn[e] = g / (nq * nk) * temp[h];
  }
  __syncthreads();
  if (tid < 48) {
    const int h = tid / 12, c = tid - h * 12;
    float* row = &attn[h * 144 + c * 12];
    float m = row[0];
    for (int d = 1; d < 12; ++d) m = fmaxf(m, row[d]);
    float s = 0.f;
    for (int d = 0; d < 12; ++d) { const float e2 = expf(row[d] - m); row[d] = e2; s += e2; }
    const float inv = 1.f / s;
    for (int d = 0; d < 12; ++d) row[d] *= inv;
  }
  __syncthreads();
  for (int e = tid; e < 2304; e += 256) {
    const int o = e / 48, j = e - o * 48;
    const int h = j / 12, d = j - h * 12;
    float s = 0.f;
    for (int c = 0; c < 12; ++c)
      s += aow[o * 48 + h * 12 + c] * attn[h * 144 + c * 12 + d];
    Mws[b * 2304 + e] = s;
  }
}

// == k4b: attn-out(dot2 streamed v, FULL unroll) + in_proj + LN2 + ffn_in ====
__global__ __launch_bounds__(256, 3) void k4b(
    char* __restrict__ region, float4* __restrict__ s0arr,
    const float* __restrict__ x, const float* __restrict__ ipw,
    const float* __restrict__ ipb, const float* __restrict__ Mws,
    const float* __restrict__ aob, const float* __restrict__ lnw,
    const float* __restrict__ lnb, const float* __restrict__ fiw,
    const float* __restrict__ fib, const float* __restrict__ opw) {
  __shared__ __align__(16) unsigned int mtp[24 * 48];   // M pairs: [j2][o]
  __shared__ __align__(16) unsigned int wgp2[24 * 192]; // fiw pairs: [c2][pos]
  __shared__ unsigned int ybuf[24 * 256];               // LN2 out pairs [c2][px]
  __shared__ float fb2[192];
  __shared__ float s_aob[48], s_lnw[48], s_lnb[48], s_opw[144];
  __shared__ float s_ipw[144], s_ipb[48];
  const int tid = threadIdx.x;
  const int b = blockIdx.x >> 8;
  const int gy = blockIdx.x & 255;
  const int n = (gy << 8) + tid;
  for (int i = tid; i < 1152; i += 256) {
    const int j2 = i / 48, o = i - j2 * 48;
    mtp[i] = fpack(Mws[b * 2304 + o * 48 + 2 * j2],
                   Mws[b * 2304 + o * 48 + 2 * j2 + 1]);
  }
  for (int i = tid; i < 4608; i += 256) {
    const int c2 = i / 192, pos = i - c2 * 192;
    const int ch = (pos & 1) ? 96 + (pos >> 1) : (pos >> 1);
    wgp2[i] = fpack(fiw[ch * 48 + 2 * c2], fiw[ch * 48 + 2 * c2 + 1]);
  }
  if (tid < 192) {
    const int ch = (tid & 1) ? 96 + (tid >> 1) : (tid >> 1);
    fb2[tid] = fib[ch];
  }
  if (tid < 144) { s_opw[tid] = opw[tid]; s_ipw[tid] = ipw[tid]; }
  if (tid < 48) {
    s_aob[tid] = aob[tid]; s_lnw[tid] = lnw[tid]; s_lnb[tid] = lnb[tid];
    s_ipb[tid] = ipb[tid];
  }
  __syncthreads();
  char* rowp = region + (size_t)((b << 8) + gy) * ROWB + (tid << 4);
  float y[48];
#pragma unroll
  for (int o = 0; o < 48; ++o) y[o] = s_aob[o];
#pragma unroll
  for (int q = 0; q < 6; ++q) {
    F4U u; u.f4 = *(const float4*)(rowp + (18 + q) * 4096);
#pragma unroll
    for (int k = 0; k < 4; ++k) {
      const unsigned int vp = u.u[k];
      const unsigned int* mr = &mtp[(4 * q + k) * 48];
#pragma unroll
      for (int o = 0; o < 48; ++o) y[o] = fdot2u(vp, mr[o], y[o]);
    }
  }
  const float x0 = x[((size_t)b * 3 + 0) * NPIX + n];
  const float x1 = x[((size_t)b * 3 + 1) * NPIX + n];
  const float x2 = x[((size_t)b * 3 + 2) * NPIX + n];
  float mu = 0.f;
#pragma unroll
  for (int c = 0; c < 48; ++c) {
    y[c] += s_ipw[c * 3] * x0 + s_ipw[c * 3 + 1] * x1 + s_ipw[c * 3 + 2] * x2 + s_ipb[c];
    mu += y[c];
  }
  float s0 = 0.f, s1 = 0.f, s2 = 0.f;
#pragma unroll
  for (int c = 0; c < 48; ++c) {
    s0 += s_opw[c] * y[c]; s1 += s_opw[48 + c] * y[c]; s2 += s_opw[96 + c] * y[c];
  }
  float4 s0v; s0v.x = s0; s0v.y = s1; s0v.z = s2; s0v.w = 0.f;
  s0arr[(size_t)b * NPIX + n] = s0v;
  mu *= (1.f / 48.f);
  float var = 0.f;
#pragma unroll
  for (int c = 0; c < 48; ++c) { const float d = y[c] - mu; var += d * d; }
  const float rs2 = rsqrtf(var * (1.f / 48.f) + 1e-6f);
#pragma unroll
  for (int c2 = 0; c2 < 24; ++c2) {
    const float a = (y[2*c2]   - mu) * rs2 * s_lnw[2*c2]   + s_lnb[2*c2];
    const float bb = (y[2*c2+1] - mu) * rs2 * s_lnw[2*c2+1] + s_lnb[2*c2+1];
    ybuf[c2 * 256 + tid] = fpack(a, bb);
  }
  __builtin_amdgcn_sched_barrier(0);   // y[48] dead; do not merge into conv
#pragma unroll 1
  for (int ob = 0; ob < 12; ++ob) {
    const int o0 = ob * 16;
    float acc[16];
#pragma unroll
    for (int j = 0; j < 16; ++j) acc[j] = fb2[o0 + j];
#pragma unroll 4
    for (int c2 = 0; c2 < 24; ++c2) {
      const unsigned int yp = ybuf[c2 * 256 + tid];
      const uint4* wr = (const uint4*)&wgp2[c2 * 192 + o0];
#pragma unroll
      for (int k = 0; k < 4; ++k) {
        const uint4 w = wr[k];
        acc[4*k+0] = fdot2u(yp, w.x, acc[4*k+0]);
        acc[4*k+1] = fdot2u(yp, w.y, acc[4*k+1]);
        acc[4*k+2] = fdot2u(yp, w.z, acc[4*k+2]);
        acc[4*k+3] = fdot2u(yp, w.w, acc[4*k+3]);
      }
    }
    F4U u;
    u.u[0] = fpack(acc[0], acc[1]);   u.u[1] = fpack(acc[2], acc[3]);
    u.u[2] = fpack(acc[4], acc[5]);   u.u[3] = fpack(acc[6], acc[7]);
    *(float4*)(rowp + (2 * ob) * 4096) = u.f4;
    u.u[0] = fpack(acc[8], acc[9]);   u.u[1] = fpack(acc[10], acc[11]);
    u.u[2] = fpack(acc[12], acc[13]); u.u[3] = fpack(acc[14], acc[15]);
    *(float4*)(rowp + (2 * ob + 1) * 4096) = u.f4;
    __builtin_amdgcn_sched_barrier(0);
  }
}

// ====== k5b: dw + SimpleGate + ffn_out + out_proj [r24 verbatim] ============
__global__ __launch_bounds__(256, 2) void k5b(
    const char* __restrict__ region, const float4* __restrict__ s0arr,
    const float* __restrict__ fdww, const float* __restrict__ fdwb,
    const float* __restrict__ fow, const float* __restrict__ fob,
    const float* __restrict__ opw, const float* __restrict__ opb,
    float* __restrict__ out) {
  __shared__ unsigned int halo[12 * HSTRIDE];
  __shared__ __align__(16) float fowT[96 * 48];   // fowT[c1][o] = fow[o][c1]
  __shared__ float s_dww2[1728], s_dwb2[192], s_opw[144], s_fob[48];
  const int tid = threadIdx.x;
  for (int i = tid; i < 4608; i += 256) {
    const int c = i / 48, o = i - c * 48;
    fowT[i] = fow[o * 96 + c];
  }
  for (int i = tid; i < 1728; i += 256) {
    const int P = i / 9, t = i - P * 9;
    const int ch = (P & 1) ? 96 + (P >> 1) : (P >> 1);
    s_dww2[i] = fdww[ch * 9 + t];
  }
  if (tid < 192) {
    const int ch = (tid & 1) ? 96 + (tid >> 1) : (tid >> 1);
    s_dwb2[tid] = fdwb[ch];
  }
  if (tid < 144) s_opw[tid] = opw[tid];
  if (tid < 48) s_fob[tid] = fob[tid];
  const int b = blockIdx.x >> 8;
  const int tile = blockIdx.x & 255;
  const int ty0 = (tile >> 4) << 4, tx0 = (tile & 15) << 4;
  const int py = tid >> 4, px = tid & 15;
  const int hp = (py + 1) * 18 + (px + 1);
  const int gn = ((ty0 + py) << 8) + (tx0 + px);
  const char* regb = region + (size_t)b * REGPB;

  float4 pf[4];
  auto prefetch = [&](int cb) {
#pragma unroll
    for (int r = 0; r < 4; ++r) {
      const int i = tid + (r << 8);
      float4 z = {0.f, 0.f, 0.f, 0.f}; pf[r] = z;
      if (i < 972) {
        const int c4 = i / 324, p = i - c4 * 324;
        const int hy = p / 18, hx = p - hy * 18;
        const int gy = ty0 + hy - 1, gx = tx0 + hx - 1;
        if (((unsigned)gy < 256u) && ((unsigned)gx < 256u))
          pf[r] = *(const float4*)(regb + (size_t)gy * ROWB + (cb + c4) * 4096 + (gx << 4));
      }
    }
  };
  auto commit = [&]() {
#pragma unroll
    for (int r = 0; r < 4; ++r) {
      const int i = tid + (r << 8);
      if (i < 972) {
        const int c4 = i / 324, p = i - c4 * 324;
        F4U u; u.f4 = pf[r];
        const int pb = c4 << 2;
#pragma unroll
        for (int j = 0; j < 4; ++j) halo[(pb + j) * HSTRIDE + p] = u.u[j];
      }
    }
  };

  float facc[48];
#pragma unroll
  for (int o = 0; o < 48; ++o) facc[o] = 0.f;
  prefetch(0);
  for (int s = 0; s < 8; ++s) {
    __syncthreads(); commit(); __syncthreads();
    if (s < 7) prefetch(3 * (s + 1));
    const int offs[9] = {-19, -18, -17, -1, 0, 1, 17, 18, 19};
#pragma unroll
    for (int pp = 0; pp < 12; ++pp) {
      const int P = 24 * s + 2 * pp;
      const float* w0 = &s_dww2[P * 9];
      const float* w1 = w0 + 9;
      const unsigned int* hrow = &halo[pp * HSTRIDE + hp];
      float a = s_dwb2[P], b2 = s_dwb2[P + 1];
#pragma unroll
      for (int t = 0; t < 9; ++t) {
        const float2 f = uh2f(hrow[offs[t]]);
        a += w0[t] * f.x; b2 += w1[t] * f.y;
      }
      const float gate = a * b2;
      const float* fr = &fowT[(12 * s + pp) * 48];
#pragma unroll
      for (int o4 = 0; o4 < 12; ++o4) {
        const float4 m = *(const float4*)&fr[o4 * 4];
        facc[o4 * 4 + 0] += m.x * gate; facc[o4 * 4 + 1] += m.y * gate;
        facc[o4 * 4 + 2] += m.z * gate; facc[o4 * 4 + 3] += m.w * gate;
      }
    }
  }
  const float4 s0v = s0arr[(size_t)b * NPIX + gn];
  float r0 = s0v.x + opb[0];
  float r1 = s0v.y + opb[1];
  float r2 = s0v.z + opb[2];
#pragma unroll
  for (int o = 0; o < 48; ++o) {
    const float f = facc[o] + s_fob[o];
    r0 += s_opw[o] * f; r1 += s_opw[48 + o] * f; r2 += s_opw[96 + o] * f;
  }
  out[((size_t)b * 3 + 0) * NPIX + gn] = r0;
  out[((size_t)b * 3 + 1) * NPIX + gn] = r1;
  out[((size_t)b * 3 + 2) * NPIX + gn] = r2;
}

extern "C" void kernel_launch(void* const* d_in, const int* in_sizes, int n_in,
                              void* d_out, int out_size, void* d_ws, size_t ws_size,
                              hipStream_t stream) {
  const float* x    = (const float*)d_in[0];
  const float* ipw  = (const float*)d_in[1];
  const float* ipb  = (const float*)d_in[2];
  const float* ln1w = (const float*)d_in[3];
  const float* ln1b = (const float*)d_in[4];
  const float* qw   = (const float*)d_in[5];
  const float* qb   = (const float*)d_in[6];
  const float* qdww = (const float*)d_in[7];
  const float* qdwb = (const float*)d_in[8];
  const float* temp = (const float*)d_in[9];
  const float* aow  = (const float*)d_in[10];
  const float* aob  = (const float*)d_in[11];
  const float* ln2w = (const float*)d_in[12];
  const float* ln2b = (const float*)d_in[13];
  const float* fiw  = (const float*)d_in[14];
  const float* fib  = (const float*)d_in[15];
  const float* fdww = (const float*)d_in[16];
  const float* fdwb = (const float*)d_in[17];
  const float* fow  = (const float*)d_in[18];
  const float* fob  = (const float*)d_in[19];
  const float* opw  = (const float*)d_in[20];
  const float* opb  = (const float*)d_in[21];

  const size_t s0Per = (size_t)NPIX * 16;
  int bc = 8;
  while (bc > 1 &&
         (size_t)bc * (REGPB + s0Per) + (5376 + 18432) * 4 > ws_size)
    bc >>= 1;
  char* region = (char*)d_ws;
  float4* s0arr = (float4*)(region + (size_t)bc * REGPB);
  float* red = (float*)((char*)s0arr + (size_t)bc * s0Per);
  float* Mws = red + 5376;
  hipMemsetAsync(red, 0, 5376 * sizeof(float), stream);
  for (int b0 = 0; b0 < 8; b0 += bc) {
    kA10<<<bc * 256, 384, 0, stream>>>(x + (size_t)b0 * 3 * NPIX, ipw, ipb,
                                       ln1w, ln1b, qw, qb, qdww, qdwb,
                                       region, red + b0 * 672);
    k3_attn<<<bc, 256, 0, stream>>>(red + b0 * 672, temp, aow,
                                    Mws + (size_t)b0 * 2304);
    k4b<<<bc * 256, 256, 0, stream>>>(region, s0arr, x + (size_t)b0 * 3 * NPIX,
                                      ipw, ipb, Mws + (size_t)b0 * 2304, aob,
                                      ln2w, ln2b, fiw, fib, opw);
    k5b<<<bc * 256, 256, 0, stream>>>(region, s0arr, fdww, fdwb, fow, fob,
                                      opw, opb,
                                      (float*)d_out + (size_t)b0 * 3 * NPIX);
  }
}

// Round 26
// 666.325 us; speedup vs baseline: 1.0736x; 1.0736x over previous
//
#include <hip/hip_runtime.h>
#include <hip/hip_fp16.h>

// CAPTNet block. B=8, CIN=3, H=W=256, DIM=48, HEADS=4 (ch=12), HID=96.
// Round 26: REVERT to round 24 (best: 667us, absmax 9.77e-4). r25's
// 384-thread kA10 dropped block residency to 1 block/CU (occupancy
// 21.9->18.1%) and regressed to 715us; the 256-thread kA9 point is better.
// Pipeline: kA9 (in_proj+LN1 analytic + qkv conv dot2 + dwconv + Gram via
// pixel-pair dot2 + v) -> k3 (attn finalize, fold attn_out_w -> M) ->
// k4b (M@v streamed dot2 + in_proj + LN2 + ffn_in dot2) -> k5b (dwconv
// pairs + SimpleGate + ffn_out + out_proj).
// region layout (r7): (b*256+gy)*98304 + chunk*4096 + gx*16, 24 chunks.
//   chunks 18..23: vdw fp16 (kA9 -> k4b); k4b writes y fp16 chunks 0..23.
// s0 (3 fp32) separate float4/pixel array (k4b -> k5b).

#define NPIX 65536
#define ROWB 98304        // bytes per (batch,row): 24 chunks * 4096
#define REGPB 25165824ull // bytes per batch in region
#define HSTRIDE 332       // k5b halo LDS row stride (half2 elems) [r7]
#define HA 324            // kA9 halo LDS row stride (u32/half2 elems)
#define KQP 129           // kA9 q/k LDS row stride in u32 (128 px-pairs + pad)

union F4U { float4 f4; unsigned int u[4]; };

typedef _Float16 h2f __attribute__((ext_vector_type(2)));
union U32H2 { unsigned int u; h2f h; };

__device__ __forceinline__ float2 uh2f(unsigned int u) {
  __half2 h; *(unsigned int*)&h = u; return __half22float2(h);
}
__device__ __forceinline__ unsigned int fpack(float a, float b) {
  __half2 h = __halves2half2(__float2half_rn(a), __float2half_rn(b));
  return *(unsigned int*)&h;
}
__device__ __forceinline__ float fdot2u(unsigned int a, unsigned int b, float c) {
  U32H2 ua, ub; ua.u = a; ub.u = b;
  return __builtin_amdgcn_fdot2(ua.h, ub.h, c, false);
}

// == kA9: in_proj+LN1(analytic)+qkv conv(dot2)+dwconv+Gram(px-pair dot2)+v ==
__global__ __launch_bounds__(256, 2) void kA9(
    const float* __restrict__ x, const float* __restrict__ ipw,
    const float* __restrict__ ipb, const float* __restrict__ lnw,
    const float* __restrict__ lnb, const float* __restrict__ qw,
    const float* __restrict__ qb, const float* __restrict__ dww,
    const float* __restrict__ dwb, char* __restrict__ region,
    float* __restrict__ red) {
  __shared__ unsigned int th[24 * HA];          // LN1 out, ch pairs fp16
  __shared__ unsigned int um[12 * HA];          // conv out 24ch fp16 pairs
  __shared__ unsigned int qsm[24 * KQP];        // q: ch-major, 2px per u32
  __shared__ unsigned int ksm[24 * KQP];        // k: ch-major, 2px per u32
  __shared__ __align__(16) unsigned int wgp[576];  // conv w fp16 pairs [c2][o]
  __shared__ float qbf[24];
  __shared__ unsigned int dwp[72 * 9];          // dw w fp16 ch-pairs
  __shared__ unsigned int dbp[72];
  __shared__ float s_ipw[144], s_ipb[48], s_lnw[48], s_lnb[48];
  __shared__ float s_C[14];   // LN1 analytic scalars
  const int tid = threadIdx.x;
  for (int i = tid; i < 648; i += 256)
    dwp[i] = fpack(dww[(i / 9) * 18 + (i % 9)], dww[(i / 9) * 18 + 9 + (i % 9)]);
  if (tid < 72) dbp[tid] = fpack(dwb[2 * tid], dwb[2 * tid + 1]);
  if (tid < 144) s_ipw[tid] = ipw[tid];
  if (tid < 48) { s_ipb[tid] = ipb[tid]; s_lnw[tid] = lnw[tid]; s_lnb[tid] = lnb[tid]; }
  if (tid >= 192 && tid < 206) {
    const int e = tid - 192;
    float s = 0.f;
    if (e < 3) {
      for (int c = 0; c < 48; ++c) s += ipw[3 * c + e];
    } else if (e == 3) {
      for (int c = 0; c < 48; ++c) s += ipb[c];
    } else if (e < 10) {
      const int k0[6] = {0, 0, 0, 1, 1, 2}, k1[6] = {0, 1, 2, 1, 2, 2};
      const int a = k0[e - 4], bq = k1[e - 4];
      for (int c = 0; c < 48; ++c) s += ipw[3 * c + a] * ipw[3 * c + bq];
    } else if (e < 13) {
      for (int c = 0; c < 48; ++c) s += ipw[3 * c + (e - 10)] * ipb[c];
    } else {
      for (int c = 0; c < 48; ++c) s += ipb[c] * ipb[c];
    }
    s_C[e] = s;
  }
  const int b = blockIdx.x >> 8;
  const int tile = blockIdx.x & 255;
  const int ty0 = (tile >> 4) << 4, tx0 = (tile & 15) << 4;
  const int py = tid >> 4, px = tid & 15;
  const int hp = (py + 1) * 18 + (px + 1);
  char* regb = region + (size_t)b * REGPB;
  const int offs[9] = {-19, -18, -17, -1, 0, 1, 17, 18, 19};
  __syncthreads();

  auto stage_px = [&](int p) {
    const int hy = p / 18, hx = p - hy * 18;
    const int gy = ty0 + hy - 1, gx = tx0 + hx - 1;
    const bool ok = ((unsigned)gy < 256u) && ((unsigned)gx < 256u);
    const int gn = (gy << 8) + gx;
    float x0 = 0.f, x1 = 0.f, x2 = 0.f;
    if (ok) {
      x0 = x[((size_t)b * 3 + 0) * NPIX + gn];
      x1 = x[((size_t)b * 3 + 1) * NPIX + gn];
      x2 = x[((size_t)b * 3 + 2) * NPIX + gn];
    }
    const float mu = (s_C[0]*x0 + s_C[1]*x1 + s_C[2]*x2 + s_C[3]) * (1.f/48.f);
    const float sumsq = s_C[4]*x0*x0 + s_C[7]*x1*x1 + s_C[9]*x2*x2
                      + 2.f*(s_C[5]*x0*x1 + s_C[6]*x0*x2 + s_C[8]*x1*x2
                             + s_C[10]*x0 + s_C[11]*x1 + s_C[12]*x2)
                      + s_C[13];
    const float var = sumsq * (1.f/48.f) - mu * mu;
    const float rs = rsqrtf(var + 1e-6f);
#pragma unroll
    for (int c2 = 0; c2 < 24; ++c2) {
      const float na = s_ipw[6*c2+0]*x0 + s_ipw[6*c2+1]*x1 + s_ipw[6*c2+2]*x2 + s_ipb[2*c2];
      const float nb = s_ipw[6*c2+3]*x0 + s_ipw[6*c2+4]*x1 + s_ipw[6*c2+5]*x2 + s_ipb[2*c2+1];
      th[c2 * HA + p] = fpack((na - mu) * rs * s_lnw[2*c2]   + s_lnb[2*c2],
                              (nb - mu) * rs * s_lnw[2*c2+1] + s_lnb[2*c2+1]);
    }
  };
  stage_px(tid);
  __builtin_amdgcn_sched_barrier(0);
  if (tid < 68) stage_px(tid + 256);
  __syncthreads();

  auto loadwg = [&](int cb) {
    for (int i = tid; i < 576; i += 256) {
      const int c2 = i / 24, o = i - c2 * 24;
      wgp[i] = fpack(qw[(cb + o) * 48 + 2 * c2], qw[(cb + o) * 48 + 2 * c2 + 1]);
    }
    if (tid < 24) qbf[tid] = qb[cb + tid];
  };
  auto conv_px = [&](int p) {
    const int hy = p / 18, hx = p - hy * 18;
    const int gy = ty0 + hy - 1, gx = tx0 + hx - 1;
    const bool ok = ((unsigned)gy < 256u) && ((unsigned)gx < 256u);
    float a[24];
#pragma unroll
    for (int j = 0; j < 24; ++j) a[j] = qbf[j];
#pragma unroll 4
    for (int c2 = 0; c2 < 24; ++c2) {
      const unsigned int t = th[c2 * HA + p];
      const uint4* wr = (const uint4*)&wgp[c2 * 24];
#pragma unroll
      for (int k = 0; k < 6; ++k) {
        const uint4 w = wr[k];
        a[4*k+0] = fdot2u(t, w.x, a[4*k+0]);
        a[4*k+1] = fdot2u(t, w.y, a[4*k+1]);
        a[4*k+2] = fdot2u(t, w.z, a[4*k+2]);
        a[4*k+3] = fdot2u(t, w.w, a[4*k+3]);
      }
    }
#pragma unroll
    for (int j = 0; j < 12; ++j)
      um[j * HA + p] = ok ? fpack(a[2 * j], a[2 * j + 1]) : 0u;
  };
  auto convPhase = [&]() {
    conv_px(tid);
    __builtin_amdgcn_sched_barrier(0);
    if (tid < 68) conv_px(tid + 256);
  };
  // dwconv 24ch -> ch-major fp16 halves in dst (2 half stores per pair)
  auto dwqk = [&](int cpb, unsigned int* dst) {
    __half* dh = (__half*)dst;
#pragma unroll
    for (int j = 0; j < 12; ++j) {
      const float2 db = uh2f(dbp[cpb + j]);
      float a = db.x, bb = db.y;
      const unsigned int* hrow = &um[j * HA + hp];
      const unsigned int* wp = &dwp[(cpb + j) * 9];
#pragma unroll
      for (int t = 0; t < 9; ++t) {
        const float2 f = uh2f(hrow[offs[t]]);
        const float2 w = uh2f(wp[t]);
        a += w.x * f.x; bb += w.y * f.y;
      }
      dh[(2 * j) * (2 * KQP) + tid]     = __float2half_rn(a);
      dh[(2 * j + 1) * (2 * KQP) + tid] = __float2half_rn(bb);
    }
  };
  auto dwv = [&](int cpb, int chunk0) {
    unsigned int vp[12];
#pragma unroll
    for (int j = 0; j < 12; ++j) {
      const float2 db = uh2f(dbp[cpb + j]);
      float a = db.x, bb = db.y;
      const unsigned int* hrow = &um[j * HA + hp];
      const unsigned int* wp = &dwp[(cpb + j) * 9];
#pragma unroll
      for (int t = 0; t < 9; ++t) {
        const float2 f = uh2f(hrow[offs[t]]);
        const float2 w = uh2f(wp[t]);
        a += w.x * f.x; bb += w.y * f.y;
      }
      vp[j] = fpack(a, bb);
    }
    char* vrow = regb + (size_t)(ty0 + py) * ROWB + ((tx0 + px) << 4);
#pragma unroll
    for (int q = 0; q < 3; ++q) {
      F4U u;
      u.u[0] = vp[4 * q]; u.u[1] = vp[4 * q + 1];
      u.u[2] = vp[4 * q + 2]; u.u[3] = vp[4 * q + 3];
      *(float4*)(vrow + (chunk0 + q) * 4096) = u.f4;
    }
  };
  // Gram/norms: 1 dot2 per pixel-pair, 4 partial accumulators.
  auto gram2 = [&](int hbase) {
    for (int e = tid; e < 336; e += 256) {
      const int hh = e / 168, r2 = e - hh * 168;
      const unsigned int *ar, *br;
      if (r2 < 144) {
        ar = &qsm[(12 * hh + r2 / 12) * KQP];
        br = &ksm[(12 * hh + r2 % 12) * KQP];
      } else if (r2 < 156) {
        ar = br = &qsm[(12 * hh + (r2 - 144)) * KQP];
      } else {
        ar = br = &ksm[(12 * hh + (r2 - 156)) * KQP];
      }
      float s0 = 0.f, s1 = 0.f, s2 = 0.f, s3 = 0.f;
#pragma unroll 8
      for (int p = 0; p < 128; p += 4) {
        s0 = fdot2u(ar[p],     br[p],     s0);
        s1 = fdot2u(ar[p + 1], br[p + 1], s1);
        s2 = fdot2u(ar[p + 2], br[p + 2], s2);
        s3 = fdot2u(ar[p + 3], br[p + 3], s3);
      }
      atomicAdd(&red[b * 672 + (hbase + hh) * 168 + r2], (s0 + s1) + (s2 + s3));
    }
  };

  loadwg(0);   __syncthreads(); convPhase(); __syncthreads(); dwqk(0, qsm);
  loadwg(48);  __syncthreads(); convPhase(); __syncthreads(); dwqk(24, ksm);
  __syncthreads(); gram2(0);
  loadwg(24);  __syncthreads(); convPhase(); __syncthreads(); dwqk(12, qsm);
  loadwg(72);  __syncthreads(); convPhase(); __syncthreads(); dwqk(36, ksm);
  __syncthreads(); gram2(2);
  loadwg(96);  __syncthreads(); convPhase(); __syncthreads(); dwv(48, 18);
  loadwg(120); __syncthreads(); convPhase(); __syncthreads(); dwv(60, 21);
}

// ================= k3: finalize attn, build fused M =========================
__global__ __launch_bounds__(256) void k3_attn(const float* __restrict__ red,
                                               const float* __restrict__ temp,
                                               const float* __restrict__ aow,
                                               float* __restrict__ Mws) {
  __shared__ float attn[4 * 144];
  const int b = blockIdx.x, tid = threadIdx.x;
  const float* rb = red + b * 672;
  for (int e = tid; e < 576; e += 256) {
    const int h = e / 144, r = e - h * 144;
    const int c = r / 12, d = r - c * 12;
    const float g = rb[h * 168 + r];
    const float nq = fmaxf(sqrtf(rb[h * 168 + 144 + c]), 1e-12f);
    const float nk = fmaxf(sqrtf(rb[h * 168 + 156 + d]), 1e-12f);
    attn[e] = g / (nq * nk) * temp[h];
  }
  __syncthreads();
  if (tid < 48) {
    const int h = tid / 12, c = tid - h * 12;
    float* row = &attn[h * 144 + c * 12];
    float m = row[0];
    for (int d = 1; d < 12; ++d) m = fmaxf(m, row[d]);
    float s = 0.f;
    for (int d = 0; d < 12; ++d) { const float e2 = expf(row[d] - m); row[d] = e2; s += e2; }
    const float inv = 1.f / s;
    for (int d = 0; d < 12; ++d) row[d] *= inv;
  }
  __syncthreads();
  for (int e = tid; e < 2304; e += 256) {
    const int o = e / 48, j = e - o * 48;
    const int h = j / 12, d = j - h * 12;
    float s = 0.f;
    for (int c = 0; c < 12; ++c)
      s += aow[o * 48 + h * 12 + c] * attn[h * 144 + c * 12 + d];
    Mws[b * 2304 + e] = s;
  }
}

// == k4b: attn-out(dot2 streamed v, FULL unroll) + in_proj + LN2 + ffn_in ====
__global__ __launch_bounds__(256, 3) void k4b(
    char* __restrict__ region, float4* __restrict__ s0arr,
    const float* __restrict__ x, const float* __restrict__ ipw,
    const float* __restrict__ ipb, const float* __restrict__ Mws,
    const float* __restrict__ aob, const float* __restrict__ lnw,
    const float* __restrict__ lnb, const float* __restrict__ fiw,
    const float* __restrict__ fib, const float* __restrict__ opw) {
  __shared__ __align__(16) unsigned int mtp[24 * 48];   // M pairs: [j2][o]
  __shared__ __align__(16) unsigned int wgp2[24 * 192]; // fiw pairs: [c2][pos]
  __shared__ unsigned int ybuf[24 * 256];               // LN2 out pairs [c2][px]
  __shared__ float fb2[192];
  __shared__ float s_aob[48], s_lnw[48], s_lnb[48], s_opw[144];
  __shared__ float s_ipw[144], s_ipb[48];
  const int tid = threadIdx.x;
  const int b = blockIdx.x >> 8;
  const int gy = blockIdx.x & 255;
  const int n = (gy << 8) + tid;
  for (int i = tid; i < 1152; i += 256) {
    const int j2 = i / 48, o = i - j2 * 48;
    mtp[i] = fpack(Mws[b * 2304 + o * 48 + 2 * j2],
                   Mws[b * 2304 + o * 48 + 2 * j2 + 1]);
  }
  for (int i = tid; i < 4608; i += 256) {
    const int c2 = i / 192, pos = i - c2 * 192;
    const int ch = (pos & 1) ? 96 + (pos >> 1) : (pos >> 1);
    wgp2[i] = fpack(fiw[ch * 48 + 2 * c2], fiw[ch * 48 + 2 * c2 + 1]);
  }
  if (tid < 192) {
    const int ch = (tid & 1) ? 96 + (tid >> 1) : (tid >> 1);
    fb2[tid] = fib[ch];
  }
  if (tid < 144) { s_opw[tid] = opw[tid]; s_ipw[tid] = ipw[tid]; }
  if (tid < 48) {
    s_aob[tid] = aob[tid]; s_lnw[tid] = lnw[tid]; s_lnb[tid] = lnb[tid];
    s_ipb[tid] = ipb[tid];
  }
  __syncthreads();
  char* rowp = region + (size_t)((b << 8) + gy) * ROWB + (tid << 4);
  float y[48];
#pragma unroll
  for (int o = 0; o < 48; ++o) y[o] = s_aob[o];
#pragma unroll
  for (int q = 0; q < 6; ++q) {
    F4U u; u.f4 = *(const float4*)(rowp + (18 + q) * 4096);
#pragma unroll
    for (int k = 0; k < 4; ++k) {
      const unsigned int vp = u.u[k];
      const unsigned int* mr = &mtp[(4 * q + k) * 48];
#pragma unroll
      for (int o = 0; o < 48; ++o) y[o] = fdot2u(vp, mr[o], y[o]);
    }
  }
  const float x0 = x[((size_t)b * 3 + 0) * NPIX + n];
  const float x1 = x[((size_t)b * 3 + 1) * NPIX + n];
  const float x2 = x[((size_t)b * 3 + 2) * NPIX + n];
  float mu = 0.f;
#pragma unroll
  for (int c = 0; c < 48; ++c) {
    y[c] += s_ipw[c * 3] * x0 + s_ipw[c * 3 + 1] * x1 + s_ipw[c * 3 + 2] * x2 + s_ipb[c];
    mu += y[c];
  }
  float s0 = 0.f, s1 = 0.f, s2 = 0.f;
#pragma unroll
  for (int c = 0; c < 48; ++c) {
    s0 += s_opw[c] * y[c]; s1 += s_opw[48 + c] * y[c]; s2 += s_opw[96 + c] * y[c];
  }
  float4 s0v; s0v.x = s0; s0v.y = s1; s0v.z = s2; s0v.w = 0.f;
  s0arr[(size_t)b * NPIX + n] = s0v;
  mu *= (1.f / 48.f);
  float var = 0.f;
#pragma unroll
  for (int c = 0; c < 48; ++c) { const float d = y[c] - mu; var += d * d; }
  const float rs2 = rsqrtf(var * (1.f / 48.f) + 1e-6f);
#pragma unroll
  for (int c2 = 0; c2 < 24; ++c2) {
    const float a = (y[2*c2]   - mu) * rs2 * s_lnw[2*c2]   + s_lnb[2*c2];
    const float bb = (y[2*c2+1] - mu) * rs2 * s_lnw[2*c2+1] + s_lnb[2*c2+1];
    ybuf[c2 * 256 + tid] = fpack(a, bb);
  }
  __builtin_amdgcn_sched_barrier(0);   // y[48] dead; do not merge into conv
#pragma unroll 1
  for (int ob = 0; ob < 12; ++ob) {
    const int o0 = ob * 16;
    float acc[16];
#pragma unroll
    for (int j = 0; j < 16; ++j) acc[j] = fb2[o0 + j];
#pragma unroll 4
    for (int c2 = 0; c2 < 24; ++c2) {
      const unsigned int yp = ybuf[c2 * 256 + tid];
      const uint4* wr = (const uint4*)&wgp2[c2 * 192 + o0];
#pragma unroll
      for (int k = 0; k < 4; ++k) {
        const uint4 w = wr[k];
        acc[4*k+0] = fdot2u(yp, w.x, acc[4*k+0]);
        acc[4*k+1] = fdot2u(yp, w.y, acc[4*k+1]);
        acc[4*k+2] = fdot2u(yp, w.z, acc[4*k+2]);
        acc[4*k+3] = fdot2u(yp, w.w, acc[4*k+3]);
      }
    }
    F4U u;
    u.u[0] = fpack(acc[0], acc[1]);   u.u[1] = fpack(acc[2], acc[3]);
    u.u[2] = fpack(acc[4], acc[5]);   u.u[3] = fpack(acc[6], acc[7]);
    *(float4*)(rowp + (2 * ob) * 4096) = u.f4;
    u.u[0] = fpack(acc[8], acc[9]);   u.u[1] = fpack(acc[10], acc[11]);
    u.u[2] = fpack(acc[12], acc[13]); u.u[3] = fpack(acc[14], acc[15]);
    *(float4*)(rowp + (2 * ob + 1) * 4096) = u.f4;
    __builtin_amdgcn_sched_barrier(0);
  }
}

// ====== k5b: dw + SimpleGate + ffn_out + out_proj ===========================
__global__ __launch_bounds__(256, 2) void k5b(
    const char* __restrict__ region, const float4* __restrict__ s0arr,
    const float* __restrict__ fdww, const float* __restrict__ fdwb,
    const float* __restrict__ fow, const float* __restrict__ fob,
    const float* __restrict__ opw, const float* __restrict__ opb,
    float* __restrict__ out) {
  __shared__ unsigned int halo[12 * HSTRIDE];
  __shared__ __align__(16) float fowT[96 * 48];   // fowT[c1][o] = fow[o][c1]
  __shared__ float s_dww2[1728], s_dwb2[192], s_opw[144], s_fob[48];
  const int tid = threadIdx.x;
  for (int i = tid; i < 4608; i += 256) {
    const int c = i / 48, o = i - c * 48;
    fowT[i] = fow[o * 96 + c];
  }
  for (int i = tid; i < 1728; i += 256) {
    const int P = i / 9, t = i - P * 9;
    const int ch = (P & 1) ? 96 + (P >> 1) : (P >> 1);
    s_dww2[i] = fdww[ch * 9 + t];
  }
  if (tid < 192) {
    const int ch = (tid & 1) ? 96 + (tid >> 1) : (tid >> 1);
    s_dwb2[tid] = fdwb[ch];
  }
  if (tid < 144) s_opw[tid] = opw[tid];
  if (tid < 48) s_fob[tid] = fob[tid];
  const int b = blockIdx.x >> 8;
  const int tile = blockIdx.x & 255;
  const int ty0 = (tile >> 4) << 4, tx0 = (tile & 15) << 4;
  const int py = tid >> 4, px = tid & 15;
  const int hp = (py + 1) * 18 + (px + 1);
  const int gn = ((ty0 + py) << 8) + (tx0 + px);
  const char* regb = region + (size_t)b * REGPB;

  float4 pf[4];
  auto prefetch = [&](int cb) {
#pragma unroll
    for (int r = 0; r < 4; ++r) {
      const int i = tid + (r << 8);
      float4 z = {0.f, 0.f, 0.f, 0.f}; pf[r] = z;
      if (i < 972) {
        const int c4 = i / 324, p = i - c4 * 324;
        const int hy = p / 18, hx = p - hy * 18;
        const int gy = ty0 + hy - 1, gx = tx0 + hx - 1;
        if (((unsigned)gy < 256u) && ((unsigned)gx < 256u))
          pf[r] = *(const float4*)(regb + (size_t)gy * ROWB + (cb + c4) * 4096 + (gx << 4));
      }
    }
  };
  auto commit = [&]() {
#pragma unroll
    for (int r = 0; r < 4; ++r) {
      const int i = tid + (r << 8);
      if (i < 972) {
        const int c4 = i / 324, p = i - c4 * 324;
        F4U u; u.f4 = pf[r];
        const int pb = c4 << 2;
#pragma unroll
        for (int j = 0; j < 4; ++j) halo[(pb + j) * HSTRIDE + p] = u.u[j];
      }
    }
  };

  float facc[48];
#pragma unroll
  for (int o = 0; o < 48; ++o) facc[o] = 0.f;
  prefetch(0);
  for (int s = 0; s < 8; ++s) {
    __syncthreads(); commit(); __syncthreads();
    if (s < 7) prefetch(3 * (s + 1));
    const int offs[9] = {-19, -18, -17, -1, 0, 1, 17, 18, 19};
#pragma unroll
    for (int pp = 0; pp < 12; ++pp) {
      const int P = 24 * s + 2 * pp;
      const float* w0 = &s_dww2[P * 9];
      const float* w1 = w0 + 9;
      const unsigned int* hrow = &halo[pp * HSTRIDE + hp];
      float a = s_dwb2[P], b2 = s_dwb2[P + 1];
#pragma unroll
      for (int t = 0; t < 9; ++t) {
        const float2 f = uh2f(hrow[offs[t]]);
        a += w0[t] * f.x; b2 += w1[t] * f.y;
      }
      const float gate = a * b2;
      const float* fr = &fowT[(12 * s + pp) * 48];
#pragma unroll
      for (int o4 = 0; o4 < 12; ++o4) {
        const float4 m = *(const float4*)&fr[o4 * 4];
        facc[o4 * 4 + 0] += m.x * gate; facc[o4 * 4 + 1] += m.y * gate;
        facc[o4 * 4 + 2] += m.z * gate; facc[o4 * 4 + 3] += m.w * gate;
      }
    }
  }
  const float4 s0v = s0arr[(size_t)b * NPIX + gn];
  float r0 = s0v.x + opb[0];
  float r1 = s0v.y + opb[1];
  float r2 = s0v.z + opb[2];
#pragma unroll
  for (int o = 0; o < 48; ++o) {
    const float f = facc[o] + s_fob[o];
    r0 += s_opw[o] * f; r1 += s_opw[48 + o] * f; r2 += s_opw[96 + o] * f;
  }
  out[((size_t)b * 3 + 0) * NPIX + gn] = r0;
  out[((size_t)b * 3 + 1) * NPIX + gn] = r1;
  out[((size_t)b * 3 + 2) * NPIX + gn] = r2;
}

extern "C" void kernel_launch(void* const* d_in, const int* in_sizes, int n_in,
                              void* d_out, int out_size, void* d_ws, size_t ws_size,
                              hipStream_t stream) {
  const float* x    = (const float*)d_in[0];
  const float* ipw  = (const float*)d_in[1];
  const float* ipb  = (const float*)d_in[2];
  const float* ln1w = (const float*)d_in[3];
  const float* ln1b = (const float*)d_in[4];
  const float* qw   = (const float*)d_in[5];
  const float* qb   = (const float*)d_in[6];
  const float* qdww = (const float*)d_in[7];
  const float* qdwb = (const float*)d_in[8];
  const float* temp = (const float*)d_in[9];
  const float* aow  = (const float*)d_in[10];
  const float* aob  = (const float*)d_in[11];
  const float* ln2w = (const float*)d_in[12];
  const float* ln2b = (const float*)d_in[13];
  const float* fiw  = (const float*)d_in[14];
  const float* fib  = (const float*)d_in[15];
  const float* fdww = (const float*)d_in[16];
  const float* fdwb = (const float*)d_in[17];
  const float* fow  = (const float*)d_in[18];
  const float* fob  = (const float*)d_in[19];
  const float* opw  = (const float*)d_in[20];
  const float* opb  = (const float*)d_in[21];

  const size_t s0Per = (size_t)NPIX * 16;
  int bc = 8;
  while (bc > 1 &&
         (size_t)bc * (REGPB + s0Per) + (5376 + 18432) * 4 > ws_size)
    bc >>= 1;
  char* region = (char*)d_ws;
  float4* s0arr = (float4*)(region + (size_t)bc * REGPB);
  float* red = (float*)((char*)s0arr + (size_t)bc * s0Per);
  float* Mws = red + 5376;
  hipMemsetAsync(red, 0, 5376 * sizeof(float), stream);
  for (int b0 = 0; b0 < 8; b0 += bc) {
    kA9<<<bc * 256, 256, 0, stream>>>(x + (size_t)b0 * 3 * NPIX, ipw, ipb,
                                      ln1w, ln1b, qw, qb, qdww, qdwb,
                                      region, red + b0 * 672);
    k3_attn<<<bc, 256, 0, stream>>>(red + b0 * 672, temp, aow,
                                    Mws + (size_t)b0 * 2304);
    k4b<<<bc * 256, 256, 0, stream>>>(region, s0arr, x + (size_t)b0 * 3 * NPIX,
                                      ipw, ipb, Mws + (size_t)b0 * 2304, aob,
                                      ln2w, ln2b, fiw, fib, opw);
    k5b<<<bc * 256, 256, 0, stream>>>(region, s0arr, fdww, fdwb, fow, fob,
                                      opw, opb,
                                      (float*)d_out + (size_t)b0 * 3 * NPIX);
  }
}

// Round 27
// 650.258 us; speedup vs baseline: 1.1002x; 1.0247x over previous
//
#include <hip/hip_runtime.h>
#include <hip/hip_fp16.h>

// CAPTNet block. B=8, CIN=3, H=W=256, DIM=48, HEADS=4 (ch=12), HID=96.
// Round 27: r26 (666us best) with kA9's dwconv taps in packed fp16.
// Op census: dwconv was kA9's biggest phase (~4.3k ops/thread) at 2 loads +
// 4 cvt + 2 fp32-FMA per channel-pair tap. um and dwp are ALREADY fp16
// channel pairs -> one v_pk_fma_f16 per tap (acc.h += w.h*f.h): saves
// ~3.2k ops/thread (~35% of kA9 VALU). dwv also drops its fpack (acc is
// already the packed pair). fp16 9-tap accumulation adds ~5e-4 relative
// (outputs were fp16-rounded anyway); expected absmax <= 1.5e-3 vs 4.5e-3.
// Only the dwqk/dwv lambdas change; k3/k4b/k5b verbatim r26.
// region layout (r7): (b*256+gy)*98304 + chunk*4096 + gx*16, 24 chunks.
//   chunks 18..23: vdw fp16 (kA9 -> k4b); k4b writes y fp16 chunks 0..23.
// s0 (3 fp32) separate float4/pixel array (k4b -> k5b).

#define NPIX 65536
#define ROWB 98304        // bytes per (batch,row): 24 chunks * 4096
#define REGPB 25165824ull // bytes per batch in region
#define HSTRIDE 332       // k5b halo LDS row stride (half2 elems) [r7]
#define HA 324            // kA9 halo LDS row stride (u32/half2 elems)
#define KQP 129           // kA9 q/k LDS row stride in u32 (128 px-pairs + pad)

union F4U { float4 f4; unsigned int u[4]; };

typedef _Float16 h2f __attribute__((ext_vector_type(2)));
union U32H2 { unsigned int u; h2f h; };

__device__ __forceinline__ float2 uh2f(unsigned int u) {
  __half2 h; *(unsigned int*)&h = u; return __half22float2(h);
}
__device__ __forceinline__ unsigned int fpack(float a, float b) {
  __half2 h = __halves2half2(__float2half_rn(a), __float2half_rn(b));
  return *(unsigned int*)&h;
}
__device__ __forceinline__ float fdot2u(unsigned int a, unsigned int b, float c) {
  U32H2 ua, ub; ua.u = a; ub.u = b;
  return __builtin_amdgcn_fdot2(ua.h, ub.h, c, false);
}

// == kA9: in_proj+LN1(analytic)+qkv conv(dot2)+dwconv(pk_fma)+Gram+v ========
__global__ __launch_bounds__(256, 2) void kA9(
    const float* __restrict__ x, const float* __restrict__ ipw,
    const float* __restrict__ ipb, const float* __restrict__ lnw,
    const float* __restrict__ lnb, const float* __restrict__ qw,
    const float* __restrict__ qb, const float* __restrict__ dww,
    const float* __restrict__ dwb, char* __restrict__ region,
    float* __restrict__ red) {
  __shared__ unsigned int th[24 * HA];          // LN1 out, ch pairs fp16
  __shared__ unsigned int um[12 * HA];          // conv out 24ch fp16 pairs
  __shared__ unsigned int qsm[24 * KQP];        // q: ch-major, 2px per u32
  __shared__ unsigned int ksm[24 * KQP];        // k: ch-major, 2px per u32
  __shared__ __align__(16) unsigned int wgp[576];  // conv w fp16 pairs [c2][o]
  __shared__ float qbf[24];
  __shared__ unsigned int dwp[72 * 9];          // dw w fp16 ch-pairs
  __shared__ unsigned int dbp[72];
  __shared__ float s_ipw[144], s_ipb[48], s_lnw[48], s_lnb[48];
  __shared__ float s_C[14];   // LN1 analytic scalars
  const int tid = threadIdx.x;
  for (int i = tid; i < 648; i += 256)
    dwp[i] = fpack(dww[(i / 9) * 18 + (i % 9)], dww[(i / 9) * 18 + 9 + (i % 9)]);
  if (tid < 72) dbp[tid] = fpack(dwb[2 * tid], dwb[2 * tid + 1]);
  if (tid < 144) s_ipw[tid] = ipw[tid];
  if (tid < 48) { s_ipb[tid] = ipb[tid]; s_lnw[tid] = lnw[tid]; s_lnb[tid] = lnb[tid]; }
  if (tid >= 192 && tid < 206) {
    const int e = tid - 192;
    float s = 0.f;
    if (e < 3) {
      for (int c = 0; c < 48; ++c) s += ipw[3 * c + e];
    } else if (e == 3) {
      for (int c = 0; c < 48; ++c) s += ipb[c];
    } else if (e < 10) {
      const int k0[6] = {0, 0, 0, 1, 1, 2}, k1[6] = {0, 1, 2, 1, 2, 2};
      const int a = k0[e - 4], bq = k1[e - 4];
      for (int c = 0; c < 48; ++c) s += ipw[3 * c + a] * ipw[3 * c + bq];
    } else if (e < 13) {
      for (int c = 0; c < 48; ++c) s += ipw[3 * c + (e - 10)] * ipb[c];
    } else {
      for (int c = 0; c < 48; ++c) s += ipb[c] * ipb[c];
    }
    s_C[e] = s;
  }
  const int b = blockIdx.x >> 8;
  const int tile = blockIdx.x & 255;
  const int ty0 = (tile >> 4) << 4, tx0 = (tile & 15) << 4;
  const int py = tid >> 4, px = tid & 15;
  const int hp = (py + 1) * 18 + (px + 1);
  char* regb = region + (size_t)b * REGPB;
  const int offs[9] = {-19, -18, -17, -1, 0, 1, 17, 18, 19};
  __syncthreads();

  auto stage_px = [&](int p) {
    const int hy = p / 18, hx = p - hy * 18;
    const int gy = ty0 + hy - 1, gx = tx0 + hx - 1;
    const bool ok = ((unsigned)gy < 256u) && ((unsigned)gx < 256u);
    const int gn = (gy << 8) + gx;
    float x0 = 0.f, x1 = 0.f, x2 = 0.f;
    if (ok) {
      x0 = x[((size_t)b * 3 + 0) * NPIX + gn];
      x1 = x[((size_t)b * 3 + 1) * NPIX + gn];
      x2 = x[((size_t)b * 3 + 2) * NPIX + gn];
    }
    const float mu = (s_C[0]*x0 + s_C[1]*x1 + s_C[2]*x2 + s_C[3]) * (1.f/48.f);
    const float sumsq = s_C[4]*x0*x0 + s_C[7]*x1*x1 + s_C[9]*x2*x2
                      + 2.f*(s_C[5]*x0*x1 + s_C[6]*x0*x2 + s_C[8]*x1*x2
                             + s_C[10]*x0 + s_C[11]*x1 + s_C[12]*x2)
                      + s_C[13];
    const float var = sumsq * (1.f/48.f) - mu * mu;
    const float rs = rsqrtf(var + 1e-6f);
#pragma unroll
    for (int c2 = 0; c2 < 24; ++c2) {
      const float na = s_ipw[6*c2+0]*x0 + s_ipw[6*c2+1]*x1 + s_ipw[6*c2+2]*x2 + s_ipb[2*c2];
      const float nb = s_ipw[6*c2+3]*x0 + s_ipw[6*c2+4]*x1 + s_ipw[6*c2+5]*x2 + s_ipb[2*c2+1];
      th[c2 * HA + p] = fpack((na - mu) * rs * s_lnw[2*c2]   + s_lnb[2*c2],
                              (nb - mu) * rs * s_lnw[2*c2+1] + s_lnb[2*c2+1]);
    }
  };
  stage_px(tid);
  __builtin_amdgcn_sched_barrier(0);
  if (tid < 68) stage_px(tid + 256);
  __syncthreads();

  auto loadwg = [&](int cb) {
    for (int i = tid; i < 576; i += 256) {
      const int c2 = i / 24, o = i - c2 * 24;
      wgp[i] = fpack(qw[(cb + o) * 48 + 2 * c2], qw[(cb + o) * 48 + 2 * c2 + 1]);
    }
    if (tid < 24) qbf[tid] = qb[cb + tid];
  };
  auto conv_px = [&](int p) {
    const int hy = p / 18, hx = p - hy * 18;
    const int gy = ty0 + hy - 1, gx = tx0 + hx - 1;
    const bool ok = ((unsigned)gy < 256u) && ((unsigned)gx < 256u);
    float a[24];
#pragma unroll
    for (int j = 0; j < 24; ++j) a[j] = qbf[j];
#pragma unroll 4
    for (int c2 = 0; c2 < 24; ++c2) {
      const unsigned int t = th[c2 * HA + p];
      const uint4* wr = (const uint4*)&wgp[c2 * 24];
#pragma unroll
      for (int k = 0; k < 6; ++k) {
        const uint4 w = wr[k];
        a[4*k+0] = fdot2u(t, w.x, a[4*k+0]);
        a[4*k+1] = fdot2u(t, w.y, a[4*k+1]);
        a[4*k+2] = fdot2u(t, w.z, a[4*k+2]);
        a[4*k+3] = fdot2u(t, w.w, a[4*k+3]);
      }
    }
#pragma unroll
    for (int j = 0; j < 12; ++j)
      um[j * HA + p] = ok ? fpack(a[2 * j], a[2 * j + 1]) : 0u;
  };
  auto convPhase = [&]() {
    conv_px(tid);
    __builtin_amdgcn_sched_barrier(0);
    if (tid < 68) conv_px(tid + 256);
  };
  // dwconv 24ch via packed fp16 fma; dst ch-major fp16 halves
  auto dwqk = [&](int cpb, unsigned int* dst) {
    __half* dh = (__half*)dst;
#pragma unroll
    for (int j = 0; j < 12; ++j) {
      U32H2 acc; acc.u = dbp[cpb + j];
      const unsigned int* hrow = &um[j * HA + hp];
      const unsigned int* wp = &dwp[(cpb + j) * 9];
#pragma unroll
      for (int t = 0; t < 9; ++t) {
        U32H2 f, w; f.u = hrow[offs[t]]; w.u = wp[t];
        acc.h = w.h * f.h + acc.h;   // v_pk_fma_f16
      }
      __half2 hv = *(__half2*)&acc.u;
      dh[(2 * j) * (2 * KQP) + tid]     = __low2half(hv);
      dh[(2 * j + 1) * (2 * KQP) + tid] = __high2half(hv);
    }
  };
  auto dwv = [&](int cpb, int chunk0) {
    unsigned int vp[12];
#pragma unroll
    for (int j = 0; j < 12; ++j) {
      U32H2 acc; acc.u = dbp[cpb + j];
      const unsigned int* hrow = &um[j * HA + hp];
      const unsigned int* wp = &dwp[(cpb + j) * 9];
#pragma unroll
      for (int t = 0; t < 9; ++t) {
        U32H2 f, w; f.u = hrow[offs[t]]; w.u = wp[t];
        acc.h = w.h * f.h + acc.h;   // v_pk_fma_f16
      }
      vp[j] = acc.u;                 // already the packed fp16 pair
    }
    char* vrow = regb + (size_t)(ty0 + py) * ROWB + ((tx0 + px) << 4);
#pragma unroll
    for (int q = 0; q < 3; ++q) {
      F4U u;
      u.u[0] = vp[4 * q]; u.u[1] = vp[4 * q + 1];
      u.u[2] = vp[4 * q + 2]; u.u[3] = vp[4 * q + 3];
      *(float4*)(vrow + (chunk0 + q) * 4096) = u.f4;
    }
  };
  // Gram/norms: 1 dot2 per pixel-pair, 4 partial accumulators.
  auto gram2 = [&](int hbase) {
    for (int e = tid; e < 336; e += 256) {
      const int hh = e / 168, r2 = e - hh * 168;
      const unsigned int *ar, *br;
      if (r2 < 144) {
        ar = &qsm[(12 * hh + r2 / 12) * KQP];
        br = &ksm[(12 * hh + r2 % 12) * KQP];
      } else if (r2 < 156) {
        ar = br = &qsm[(12 * hh + (r2 - 144)) * KQP];
      } else {
        ar = br = &ksm[(12 * hh + (r2 - 156)) * KQP];
      }
      float s0 = 0.f, s1 = 0.f, s2 = 0.f, s3 = 0.f;
#pragma unroll 8
      for (int p = 0; p < 128; p += 4) {
        s0 = fdot2u(ar[p],     br[p],     s0);
        s1 = fdot2u(ar[p + 1], br[p + 1], s1);
        s2 = fdot2u(ar[p + 2], br[p + 2], s2);
        s3 = fdot2u(ar[p + 3], br[p + 3], s3);
      }
      atomicAdd(&red[b * 672 + (hbase + hh) * 168 + r2], (s0 + s1) + (s2 + s3));
    }
  };

  loadwg(0);   __syncthreads(); convPhase(); __syncthreads(); dwqk(0, qsm);
  loadwg(48);  __syncthreads(); convPhase(); __syncthreads(); dwqk(24, ksm);
  __syncthreads(); gram2(0);
  loadwg(24);  __syncthreads(); convPhase(); __syncthreads(); dwqk(12, qsm);
  loadwg(72);  __syncthreads(); convPhase(); __syncthreads(); dwqk(36, ksm);
  __syncthreads(); gram2(2);
  loadwg(96);  __syncthreads(); convPhase(); __syncthreads(); dwv(48, 18);
  loadwg(120); __syncthreads(); convPhase(); __syncthreads(); dwv(60, 21);
}

// ================= k3: finalize attn, build fused M [r26 verbatim] ==========
__global__ __launch_bounds__(256) void k3_attn(const float* __restrict__ red,
                                               const float* __restrict__ temp,
                                               const float* __restrict__ aow,
                                               float* __restrict__ Mws) {
  __shared__ float attn[4 * 144];
  const int b = blockIdx.x, tid = threadIdx.x;
  const float* rb = red + b * 672;
  for (int e = tid; e < 576; e += 256) {
    const int h = e / 144, r = e - h * 144;
    const int c = r / 12, d = r - c * 12;
    const float g = rb[h * 168 + r];
    const float nq = fmaxf(sqrtf(rb[h * 168 + 144 + c]), 1e-12f);
    const float nk = fmaxf(sqrtf(rb[h * 168 + 156 + d]), 1e-12f);
    attn[e] = g / (nq * nk) * temp[h];
  }
  __syncthreads();
  if (tid < 48) {
    const int h = tid / 12, c = tid - h * 12;
    float* row = &attn[h * 144 + c * 12];
    float m = row[0];
    for (int d = 1; d < 12; ++d) m = fmaxf(m, row[d]);
    float s = 0.f;
    for (int d = 0; d < 12; ++d) { const float e2 = expf(row[d] - m); row[d] = e2; s += e2; }
    const float inv = 1.f / s;
    for (int d = 0; d < 12; ++d) row[d] *= inv;
  }
  __syncthreads();
  for (int e = tid; e < 2304; e += 256) {
    const int o = e / 48, j = e - o * 48;
    const int h = j / 12, d = j - h * 12;
    float s = 0.f;
    for (int c = 0; c < 12; ++c)
      s += aow[o * 48 + h * 12 + c] * attn[h * 144 + c * 12 + d];
    Mws[b * 2304 + e] = s;
  }
}

// == k4b: attn-out(dot2 streamed v, FULL unroll) + in_proj + LN2 + ffn_in ====
__global__ __launch_bounds__(256, 3) void k4b(
    char* __restrict__ region, float4* __restrict__ s0arr,
    const float* __restrict__ x, const float* __restrict__ ipw,
    const float* __restrict__ ipb, const float* __restrict__ Mws,
    const float* __restrict__ aob, const float* __restrict__ lnw,
    const float* __restrict__ lnb, const float* __restrict__ fiw,
    const float* __restrict__ fib, const float* __restrict__ opw) {
  __shared__ __align__(16) unsigned int mtp[24 * 48];   // M pairs: [j2][o]
  __shared__ __align__(16) unsigned int wgp2[24 * 192]; // fiw pairs: [c2][pos]
  __shared__ unsigned int ybuf[24 * 256];               // LN2 out pairs [c2][px]
  __shared__ float fb2[192];
  __shared__ float s_aob[48], s_lnw[48], s_lnb[48], s_opw[144];
  __shared__ float s_ipw[144], s_ipb[48];
  const int tid = threadIdx.x;
  const int b = blockIdx.x >> 8;
  const int gy = blockIdx.x & 255;
  const int n = (gy << 8) + tid;
  for (int i = tid; i < 1152; i += 256) {
    const int j2 = i / 48, o = i - j2 * 48;
    mtp[i] = fpack(Mws[b * 2304 + o * 48 + 2 * j2],
                   Mws[b * 2304 + o * 48 + 2 * j2 + 1]);
  }
  for (int i = tid; i < 4608; i += 256) {
    const int c2 = i / 192, pos = i - c2 * 192;
    const int ch = (pos & 1) ? 96 + (pos >> 1) : (pos >> 1);
    wgp2[i] = fpack(fiw[ch * 48 + 2 * c2], fiw[ch * 48 + 2 * c2 + 1]);
  }
  if (tid < 192) {
    const int ch = (tid & 1) ? 96 + (tid >> 1) : (tid >> 1);
    fb2[tid] = fib[ch];
  }
  if (tid < 144) { s_opw[tid] = opw[tid]; s_ipw[tid] = ipw[tid]; }
  if (tid < 48) {
    s_aob[tid] = aob[tid]; s_lnw[tid] = lnw[tid]; s_lnb[tid] = lnb[tid];
    s_ipb[tid] = ipb[tid];
  }
  __syncthreads();
  char* rowp = region + (size_t)((b << 8) + gy) * ROWB + (tid << 4);
  float y[48];
#pragma unroll
  for (int o = 0; o < 48; ++o) y[o] = s_aob[o];
#pragma unroll
  for (int q = 0; q < 6; ++q) {
    F4U u; u.f4 = *(const float4*)(rowp + (18 + q) * 4096);
#pragma unroll
    for (int k = 0; k < 4; ++k) {
      const unsigned int vp = u.u[k];
      const unsigned int* mr = &mtp[(4 * q + k) * 48];
#pragma unroll
      for (int o = 0; o < 48; ++o) y[o] = fdot2u(vp, mr[o], y[o]);
    }
  }
  const float x0 = x[((size_t)b * 3 + 0) * NPIX + n];
  const float x1 = x[((size_t)b * 3 + 1) * NPIX + n];
  const float x2 = x[((size_t)b * 3 + 2) * NPIX + n];
  float mu = 0.f;
#pragma unroll
  for (int c = 0; c < 48; ++c) {
    y[c] += s_ipw[c * 3] * x0 + s_ipw[c * 3 + 1] * x1 + s_ipw[c * 3 + 2] * x2 + s_ipb[c];
    mu += y[c];
  }
  float s0 = 0.f, s1 = 0.f, s2 = 0.f;
#pragma unroll
  for (int c = 0; c < 48; ++c) {
    s0 += s_opw[c] * y[c]; s1 += s_opw[48 + c] * y[c]; s2 += s_opw[96 + c] * y[c];
  }
  float4 s0v; s0v.x = s0; s0v.y = s1; s0v.z = s2; s0v.w = 0.f;
  s0arr[(size_t)b * NPIX + n] = s0v;
  mu *= (1.f / 48.f);
  float var = 0.f;
#pragma unroll
  for (int c = 0; c < 48; ++c) { const float d = y[c] - mu; var += d * d; }
  const float rs2 = rsqrtf(var * (1.f / 48.f) + 1e-6f);
#pragma unroll
  for (int c2 = 0; c2 < 24; ++c2) {
    const float a = (y[2*c2]   - mu) * rs2 * s_lnw[2*c2]   + s_lnb[2*c2];
    const float bb = (y[2*c2+1] - mu) * rs2 * s_lnw[2*c2+1] + s_lnb[2*c2+1];
    ybuf[c2 * 256 + tid] = fpack(a, bb);
  }
  __builtin_amdgcn_sched_barrier(0);   // y[48] dead; do not merge into conv
#pragma unroll 1
  for (int ob = 0; ob < 12; ++ob) {
    const int o0 = ob * 16;
    float acc[16];
#pragma unroll
    for (int j = 0; j < 16; ++j) acc[j] = fb2[o0 + j];
#pragma unroll 4
    for (int c2 = 0; c2 < 24; ++c2) {
      const unsigned int yp = ybuf[c2 * 256 + tid];
      const uint4* wr = (const uint4*)&wgp2[c2 * 192 + o0];
#pragma unroll
      for (int k = 0; k < 4; ++k) {
        const uint4 w = wr[k];
        acc[4*k+0] = fdot2u(yp, w.x, acc[4*k+0]);
        acc[4*k+1] = fdot2u(yp, w.y, acc[4*k+1]);
        acc[4*k+2] = fdot2u(yp, w.z, acc[4*k+2]);
        acc[4*k+3] = fdot2u(yp, w.w, acc[4*k+3]);
      }
    }
    F4U u;
    u.u[0] = fpack(acc[0], acc[1]);   u.u[1] = fpack(acc[2], acc[3]);
    u.u[2] = fpack(acc[4], acc[5]);   u.u[3] = fpack(acc[6], acc[7]);
    *(float4*)(rowp + (2 * ob) * 4096) = u.f4;
    u.u[0] = fpack(acc[8], acc[9]);   u.u[1] = fpack(acc[10], acc[11]);
    u.u[2] = fpack(acc[12], acc[13]); u.u[3] = fpack(acc[14], acc[15]);
    *(float4*)(rowp + (2 * ob + 1) * 4096) = u.f4;
    __builtin_amdgcn_sched_barrier(0);
  }
}

// ====== k5b: dw + SimpleGate + ffn_out + out_proj [r26 verbatim] ============
__global__ __launch_bounds__(256, 2) void k5b(
    const char* __restrict__ region, const float4* __restrict__ s0arr,
    const float* __restrict__ fdww, const float* __restrict__ fdwb,
    const float* __restrict__ fow, const float* __restrict__ fob,
    const float* __restrict__ opw, const float* __restrict__ opb,
    float* __restrict__ out) {
  __shared__ unsigned int halo[12 * HSTRIDE];
  __shared__ __align__(16) float fowT[96 * 48];   // fowT[c1][o] = fow[o][c1]
  __shared__ float s_dww2[1728], s_dwb2[192], s_opw[144], s_fob[48];
  const int tid = threadIdx.x;
  for (int i = tid; i < 4608; i += 256) {
    const int c = i / 48, o = i - c * 48;
    fowT[i] = fow[o * 96 + c];
  }
  for (int i = tid; i < 1728; i += 256) {
    const int P = i / 9, t = i - P * 9;
    const int ch = (P & 1) ? 96 + (P >> 1) : (P >> 1);
    s_dww2[i] = fdww[ch * 9 + t];
  }
  if (tid < 192) {
    const int ch = (tid & 1) ? 96 + (tid >> 1) : (tid >> 1);
    s_dwb2[tid] = fdwb[ch];
  }
  if (tid < 144) s_opw[tid] = opw[tid];
  if (tid < 48) s_fob[tid] = fob[tid];
  const int b = blockIdx.x >> 8;
  const int tile = blockIdx.x & 255;
  const int ty0 = (tile >> 4) << 4, tx0 = (tile & 15) << 4;
  const int py = tid >> 4, px = tid & 15;
  const int hp = (py + 1) * 18 + (px + 1);
  const int gn = ((ty0 + py) << 8) + (tx0 + px);
  const char* regb = region + (size_t)b * REGPB;

  float4 pf[4];
  auto prefetch = [&](int cb) {
#pragma unroll
    for (int r = 0; r < 4; ++r) {
      const int i = tid + (r << 8);
      float4 z = {0.f, 0.f, 0.f, 0.f}; pf[r] = z;
      if (i < 972) {
        const int c4 = i / 324, p = i - c4 * 324;
        const int hy = p / 18, hx = p - hy * 18;
        const int gy = ty0 + hy - 1, gx = tx0 + hx - 1;
        if (((unsigned)gy < 256u) && ((unsigned)gx < 256u))
          pf[r] = *(const float4*)(regb + (size_t)gy * ROWB + (cb + c4) * 4096 + (gx << 4));
      }
    }
  };
  auto commit = [&]() {
#pragma unroll
    for (int r = 0; r < 4; ++r) {
      const int i = tid + (r << 8);
      if (i < 972) {
        const int c4 = i / 324, p = i - c4 * 324;
        F4U u; u.f4 = pf[r];
        const int pb = c4 << 2;
#pragma unroll
        for (int j = 0; j < 4; ++j) halo[(pb + j) * HSTRIDE + p] = u.u[j];
      }
    }
  };

  float facc[48];
#pragma unroll
  for (int o = 0; o < 48; ++o) facc[o] = 0.f;
  prefetch(0);
  for (int s = 0; s < 8; ++s) {
    __syncthreads(); commit(); __syncthreads();
    if (s < 7) prefetch(3 * (s + 1));
    const int offs[9] = {-19, -18, -17, -1, 0, 1, 17, 18, 19};
#pragma unroll
    for (int pp = 0; pp < 12; ++pp) {
      const int P = 24 * s + 2 * pp;
      const float* w0 = &s_dww2[P * 9];
      const float* w1 = w0 + 9;
      const unsigned int* hrow = &halo[pp * HSTRIDE + hp];
      float a = s_dwb2[P], b2 = s_dwb2[P + 1];
#pragma unroll
      for (int t = 0; t < 9; ++t) {
        const float2 f = uh2f(hrow[offs[t]]);
        a += w0[t] * f.x; b2 += w1[t] * f.y;
      }
      const float gate = a * b2;
      const float* fr = &fowT[(12 * s + pp) * 48];
#pragma unroll
      for (int o4 = 0; o4 < 12; ++o4) {
        const float4 m = *(const float4*)&fr[o4 * 4];
        facc[o4 * 4 + 0] += m.x * gate; facc[o4 * 4 + 1] += m.y * gate;
        facc[o4 * 4 + 2] += m.z * gate; facc[o4 * 4 + 3] += m.w * gate;
      }
    }
  }
  const float4 s0v = s0arr[(size_t)b * NPIX + gn];
  float r0 = s0v.x + opb[0];
  float r1 = s0v.y + opb[1];
  float r2 = s0v.z + opb[2];
#pragma unroll
  for (int o = 0; o < 48; ++o) {
    const float f = facc[o] + s_fob[o];
    r0 += s_opw[o] * f; r1 += s_opw[48 + o] * f; r2 += s_opw[96 + o] * f;
  }
  out[((size_t)b * 3 + 0) * NPIX + gn] = r0;
  out[((size_t)b * 3 + 1) * NPIX + gn] = r1;
  out[((size_t)b * 3 + 2) * NPIX + gn] = r2;
}

extern "C" void kernel_launch(void* const* d_in, const int* in_sizes, int n_in,
                              void* d_out, int out_size, void* d_ws, size_t ws_size,
                              hipStream_t stream) {
  const float* x    = (const float*)d_in[0];
  const float* ipw  = (const float*)d_in[1];
  const float* ipb  = (const float*)d_in[2];
  const float* ln1w = (const float*)d_in[3];
  const float* ln1b = (const float*)d_in[4];
  const float* qw   = (const float*)d_in[5];
  const float* qb   = (const float*)d_in[6];
  const float* qdww = (const float*)d_in[7];
  const float* qdwb = (const float*)d_in[8];
  const float* temp = (const float*)d_in[9];
  const float* aow  = (const float*)d_in[10];
  const float* aob  = (const float*)d_in[11];
  const float* ln2w = (const float*)d_in[12];
  const float* ln2b = (const float*)d_in[13];
  const float* fiw  = (const float*)d_in[14];
  const float* fib  = (const float*)d_in[15];
  const float* fdww = (const float*)d_in[16];
  const float* fdwb = (const float*)d_in[17];
  const float* fow  = (const float*)d_in[18];
  const float* fob  = (const float*)d_in[19];
  const float* opw  = (const float*)d_in[20];
  const float* opb  = (const float*)d_in[21];

  const size_t s0Per = (size_t)NPIX * 16;
  int bc = 8;
  while (bc > 1 &&
         (size_t)bc * (REGPB + s0Per) + (5376 + 18432) * 4 > ws_size)
    bc >>= 1;
  char* region = (char*)d_ws;
  float4* s0arr = (float4*)(region + (size_t)bc * REGPB);
  float* red = (float*)((char*)s0arr + (size_t)bc * s0Per);
  float* Mws = red + 5376;
  hipMemsetAsync(red, 0, 5376 * sizeof(float), stream);
  for (int b0 = 0; b0 < 8; b0 += bc) {
    kA9<<<bc * 256, 256, 0, stream>>>(x + (size_t)b0 * 3 * NPIX, ipw, ipb,
                                      ln1w, ln1b, qw, qb, qdww, qdwb,
                                      region, red + b0 * 672);
    k3_attn<<<bc, 256, 0, stream>>>(red + b0 * 672, temp, aow,
                                    Mws + (size_t)b0 * 2304);
    k4b<<<bc * 256, 256, 0, stream>>>(region, s0arr, x + (size_t)b0 * 3 * NPIX,
                                      ipw, ipb, Mws + (size_t)b0 * 2304, aob,
                                      ln2w, ln2b, fiw, fib, opw);
    k5b<<<bc * 256, 256, 0, stream>>>(region, s0arr, fdww, fdwb, fow, fob,
                                      opw, opb,
                                      (float*)d_out + (size_t)b0 * 3 * NPIX);
  }
}

// Round 28
// 630.973 us; speedup vs baseline: 1.1338x; 1.0306x over previous
//
#include <hip/hip_runtime.h>
#include <hip/hip_fp16.h>

// CAPTNet block. B=8, CIN=3, H=W=256, DIM=48, HEADS=4 (ch=12), HID=96.
// Round 28: r27 (650us best) with k5b's dwconv taps in packed fp16 --
// the same transform that took kA9 347->329 in r27 (twice-validated).
// k5b's halo is already fp16 pairs (y_ch, y_{96+ch}); packing fdww the
// same way turns each tap into 1 load + 1 v_pk_fma_f16 (was 1 load +
// 2 cvt + 2 fp32 FMA): ~2.6k ops/thread saved (~35% of k5b VALU), and
// dwconv weight LDS halves. Gate = one unpack per pair. Numerics: fp16
// 9-tap accum on fp16-rounded y, gate error ~1e-4 through 0.05-scale
// projections. kA9/k3/k4b verbatim r27.
// region layout (r7): (b*256+gy)*98304 + chunk*4096 + gx*16, 24 chunks.
//   chunks 18..23: vdw fp16 (kA9 -> k4b); k4b writes y fp16 chunks 0..23.
// s0 (3 fp32) separate float4/pixel array (k4b -> k5b).

#define NPIX 65536
#define ROWB 98304        // bytes per (batch,row): 24 chunks * 4096
#define REGPB 25165824ull // bytes per batch in region
#define HSTRIDE 332       // k5b halo LDS row stride (half2 elems) [r7]
#define HA 324            // kA9 halo LDS row stride (u32/half2 elems)
#define KQP 129           // kA9 q/k LDS row stride in u32 (128 px-pairs + pad)

union F4U { float4 f4; unsigned int u[4]; };

typedef _Float16 h2f __attribute__((ext_vector_type(2)));
union U32H2 { unsigned int u; h2f h; };

__device__ __forceinline__ float2 uh2f(unsigned int u) {
  __half2 h; *(unsigned int*)&h = u; return __half22float2(h);
}
__device__ __forceinline__ unsigned int fpack(float a, float b) {
  __half2 h = __halves2half2(__float2half_rn(a), __float2half_rn(b));
  return *(unsigned int*)&h;
}
__device__ __forceinline__ float fdot2u(unsigned int a, unsigned int b, float c) {
  U32H2 ua, ub; ua.u = a; ub.u = b;
  return __builtin_amdgcn_fdot2(ua.h, ub.h, c, false);
}

// == kA9: in_proj+LN1(analytic)+qkv conv(dot2)+dwconv(pk_fma)+Gram+v ========
__global__ __launch_bounds__(256, 2) void kA9(
    const float* __restrict__ x, const float* __restrict__ ipw,
    const float* __restrict__ ipb, const float* __restrict__ lnw,
    const float* __restrict__ lnb, const float* __restrict__ qw,
    const float* __restrict__ qb, const float* __restrict__ dww,
    const float* __restrict__ dwb, char* __restrict__ region,
    float* __restrict__ red) {
  __shared__ unsigned int th[24 * HA];          // LN1 out, ch pairs fp16
  __shared__ unsigned int um[12 * HA];          // conv out 24ch fp16 pairs
  __shared__ unsigned int qsm[24 * KQP];        // q: ch-major, 2px per u32
  __shared__ unsigned int ksm[24 * KQP];        // k: ch-major, 2px per u32
  __shared__ __align__(16) unsigned int wgp[576];  // conv w fp16 pairs [c2][o]
  __shared__ float qbf[24];
  __shared__ unsigned int dwp[72 * 9];          // dw w fp16 ch-pairs
  __shared__ unsigned int dbp[72];
  __shared__ float s_ipw[144], s_ipb[48], s_lnw[48], s_lnb[48];
  __shared__ float s_C[14];   // LN1 analytic scalars
  const int tid = threadIdx.x;
  for (int i = tid; i < 648; i += 256)
    dwp[i] = fpack(dww[(i / 9) * 18 + (i % 9)], dww[(i / 9) * 18 + 9 + (i % 9)]);
  if (tid < 72) dbp[tid] = fpack(dwb[2 * tid], dwb[2 * tid + 1]);
  if (tid < 144) s_ipw[tid] = ipw[tid];
  if (tid < 48) { s_ipb[tid] = ipb[tid]; s_lnw[tid] = lnw[tid]; s_lnb[tid] = lnb[tid]; }
  if (tid >= 192 && tid < 206) {
    const int e = tid - 192;
    float s = 0.f;
    if (e < 3) {
      for (int c = 0; c < 48; ++c) s += ipw[3 * c + e];
    } else if (e == 3) {
      for (int c = 0; c < 48; ++c) s += ipb[c];
    } else if (e < 10) {
      const int k0[6] = {0, 0, 0, 1, 1, 2}, k1[6] = {0, 1, 2, 1, 2, 2};
      const int a = k0[e - 4], bq = k1[e - 4];
      for (int c = 0; c < 48; ++c) s += ipw[3 * c + a] * ipw[3 * c + bq];
    } else if (e < 13) {
      for (int c = 0; c < 48; ++c) s += ipw[3 * c + (e - 10)] * ipb[c];
    } else {
      for (int c = 0; c < 48; ++c) s += ipb[c] * ipb[c];
    }
    s_C[e] = s;
  }
  const int b = blockIdx.x >> 8;
  const int tile = blockIdx.x & 255;
  const int ty0 = (tile >> 4) << 4, tx0 = (tile & 15) << 4;
  const int py = tid >> 4, px = tid & 15;
  const int hp = (py + 1) * 18 + (px + 1);
  char* regb = region + (size_t)b * REGPB;
  const int offs[9] = {-19, -18, -17, -1, 0, 1, 17, 18, 19};
  __syncthreads();

  auto stage_px = [&](int p) {
    const int hy = p / 18, hx = p - hy * 18;
    const int gy = ty0 + hy - 1, gx = tx0 + hx - 1;
    const bool ok = ((unsigned)gy < 256u) && ((unsigned)gx < 256u);
    const int gn = (gy << 8) + gx;
    float x0 = 0.f, x1 = 0.f, x2 = 0.f;
    if (ok) {
      x0 = x[((size_t)b * 3 + 0) * NPIX + gn];
      x1 = x[((size_t)b * 3 + 1) * NPIX + gn];
      x2 = x[((size_t)b * 3 + 2) * NPIX + gn];
    }
    const float mu = (s_C[0]*x0 + s_C[1]*x1 + s_C[2]*x2 + s_C[3]) * (1.f/48.f);
    const float sumsq = s_C[4]*x0*x0 + s_C[7]*x1*x1 + s_C[9]*x2*x2
                      + 2.f*(s_C[5]*x0*x1 + s_C[6]*x0*x2 + s_C[8]*x1*x2
                             + s_C[10]*x0 + s_C[11]*x1 + s_C[12]*x2)
                      + s_C[13];
    const float var = sumsq * (1.f/48.f) - mu * mu;
    const float rs = rsqrtf(var + 1e-6f);
#pragma unroll
    for (int c2 = 0; c2 < 24; ++c2) {
      const float na = s_ipw[6*c2+0]*x0 + s_ipw[6*c2+1]*x1 + s_ipw[6*c2+2]*x2 + s_ipb[2*c2];
      const float nb = s_ipw[6*c2+3]*x0 + s_ipw[6*c2+4]*x1 + s_ipw[6*c2+5]*x2 + s_ipb[2*c2+1];
      th[c2 * HA + p] = fpack((na - mu) * rs * s_lnw[2*c2]   + s_lnb[2*c2],
                              (nb - mu) * rs * s_lnw[2*c2+1] + s_lnb[2*c2+1]);
    }
  };
  stage_px(tid);
  __builtin_amdgcn_sched_barrier(0);
  if (tid < 68) stage_px(tid + 256);
  __syncthreads();

  auto loadwg = [&](int cb) {
    for (int i = tid; i < 576; i += 256) {
      const int c2 = i / 24, o = i - c2 * 24;
      wgp[i] = fpack(qw[(cb + o) * 48 + 2 * c2], qw[(cb + o) * 48 + 2 * c2 + 1]);
    }
    if (tid < 24) qbf[tid] = qb[cb + tid];
  };
  auto conv_px = [&](int p) {
    const int hy = p / 18, hx = p - hy * 18;
    const int gy = ty0 + hy - 1, gx = tx0 + hx - 1;
    const bool ok = ((unsigned)gy < 256u) && ((unsigned)gx < 256u);
    float a[24];
#pragma unroll
    for (int j = 0; j < 24; ++j) a[j] = qbf[j];
#pragma unroll 4
    for (int c2 = 0; c2 < 24; ++c2) {
      const unsigned int t = th[c2 * HA + p];
      const uint4* wr = (const uint4*)&wgp[c2 * 24];
#pragma unroll
      for (int k = 0; k < 6; ++k) {
        const uint4 w = wr[k];
        a[4*k+0] = fdot2u(t, w.x, a[4*k+0]);
        a[4*k+1] = fdot2u(t, w.y, a[4*k+1]);
        a[4*k+2] = fdot2u(t, w.z, a[4*k+2]);
        a[4*k+3] = fdot2u(t, w.w, a[4*k+3]);
      }
    }
#pragma unroll
    for (int j = 0; j < 12; ++j)
      um[j * HA + p] = ok ? fpack(a[2 * j], a[2 * j + 1]) : 0u;
  };
  auto convPhase = [&]() {
    conv_px(tid);
    __builtin_amdgcn_sched_barrier(0);
    if (tid < 68) conv_px(tid + 256);
  };
  // dwconv 24ch via packed fp16 fma; dst ch-major fp16 halves
  auto dwqk = [&](int cpb, unsigned int* dst) {
    __half* dh = (__half*)dst;
#pragma unroll
    for (int j = 0; j < 12; ++j) {
      U32H2 acc; acc.u = dbp[cpb + j];
      const unsigned int* hrow = &um[j * HA + hp];
      const unsigned int* wp = &dwp[(cpb + j) * 9];
#pragma unroll
      for (int t = 0; t < 9; ++t) {
        U32H2 f, w; f.u = hrow[offs[t]]; w.u = wp[t];
        acc.h = w.h * f.h + acc.h;   // v_pk_fma_f16
      }
      __half2 hv = *(__half2*)&acc.u;
      dh[(2 * j) * (2 * KQP) + tid]     = __low2half(hv);
      dh[(2 * j + 1) * (2 * KQP) + tid] = __high2half(hv);
    }
  };
  auto dwv = [&](int cpb, int chunk0) {
    unsigned int vp[12];
#pragma unroll
    for (int j = 0; j < 12; ++j) {
      U32H2 acc; acc.u = dbp[cpb + j];
      const unsigned int* hrow = &um[j * HA + hp];
      const unsigned int* wp = &dwp[(cpb + j) * 9];
#pragma unroll
      for (int t = 0; t < 9; ++t) {
        U32H2 f, w; f.u = hrow[offs[t]]; w.u = wp[t];
        acc.h = w.h * f.h + acc.h;   // v_pk_fma_f16
      }
      vp[j] = acc.u;                 // already the packed fp16 pair
    }
    char* vrow = regb + (size_t)(ty0 + py) * ROWB + ((tx0 + px) << 4);
#pragma unroll
    for (int q = 0; q < 3; ++q) {
      F4U u;
      u.u[0] = vp[4 * q]; u.u[1] = vp[4 * q + 1];
      u.u[2] = vp[4 * q + 2]; u.u[3] = vp[4 * q + 3];
      *(float4*)(vrow + (chunk0 + q) * 4096) = u.f4;
    }
  };
  // Gram/norms: 1 dot2 per pixel-pair, 4 partial accumulators.
  auto gram2 = [&](int hbase) {
    for (int e = tid; e < 336; e += 256) {
      const int hh = e / 168, r2 = e - hh * 168;
      const unsigned int *ar, *br;
      if (r2 < 144) {
        ar = &qsm[(12 * hh + r2 / 12) * KQP];
        br = &ksm[(12 * hh + r2 % 12) * KQP];
      } else if (r2 < 156) {
        ar = br = &qsm[(12 * hh + (r2 - 144)) * KQP];
      } else {
        ar = br = &ksm[(12 * hh + (r2 - 156)) * KQP];
      }
      float s0 = 0.f, s1 = 0.f, s2 = 0.f, s3 = 0.f;
#pragma unroll 8
      for (int p = 0; p < 128; p += 4) {
        s0 = fdot2u(ar[p],     br[p],     s0);
        s1 = fdot2u(ar[p + 1], br[p + 1], s1);
        s2 = fdot2u(ar[p + 2], br[p + 2], s2);
        s3 = fdot2u(ar[p + 3], br[p + 3], s3);
      }
      atomicAdd(&red[b * 672 + (hbase + hh) * 168 + r2], (s0 + s1) + (s2 + s3));
    }
  };

  loadwg(0);   __syncthreads(); convPhase(); __syncthreads(); dwqk(0, qsm);
  loadwg(48);  __syncthreads(); convPhase(); __syncthreads(); dwqk(24, ksm);
  __syncthreads(); gram2(0);
  loadwg(24);  __syncthreads(); convPhase(); __syncthreads(); dwqk(12, qsm);
  loadwg(72);  __syncthreads(); convPhase(); __syncthreads(); dwqk(36, ksm);
  __syncthreads(); gram2(2);
  loadwg(96);  __syncthreads(); convPhase(); __syncthreads(); dwv(48, 18);
  loadwg(120); __syncthreads(); convPhase(); __syncthreads(); dwv(60, 21);
}

// ================= k3: finalize attn, build fused M [r27 verbatim] ==========
__global__ __launch_bounds__(256) void k3_attn(const float* __restrict__ red,
                                               const float* __restrict__ temp,
                                               const float* __restrict__ aow,
                                               float* __restrict__ Mws) {
  __shared__ float attn[4 * 144];
  const int b = blockIdx.x, tid = threadIdx.x;
  const float* rb = red + b * 672;
  for (int e = tid; e < 576; e += 256) {
    const int h = e / 144, r = e - h * 144;
    const int c = r / 12, d = r - c * 12;
    const float g = rb[h * 168 + r];
    const float nq = fmaxf(sqrtf(rb[h * 168 + 144 + c]), 1e-12f);
    const float nk = fmaxf(sqrtf(rb[h * 168 + 156 + d]), 1e-12f);
    attn[e] = g / (nq * nk) * temp[h];
  }
  __syncthreads();
  if (tid < 48) {
    const int h = tid / 12, c = tid - h * 12;
    float* row = &attn[h * 144 + c * 12];
    float m = row[0];
    for (int d = 1; d < 12; ++d) m = fmaxf(m, row[d]);
    float s = 0.f;
    for (int d = 0; d < 12; ++d) { const float e2 = expf(row[d] - m); row[d] = e2; s += e2; }
    const float inv = 1.f / s;
    for (int d = 0; d < 12; ++d) row[d] *= inv;
  }
  __syncthreads();
  for (int e = tid; e < 2304; e += 256) {
    const int o = e / 48, j = e - o * 48;
    const int h = j / 12, d = j - h * 12;
    float s = 0.f;
    for (int c = 0; c < 12; ++c)
      s += aow[o * 48 + h * 12 + c] * attn[h * 144 + c * 12 + d];
    Mws[b * 2304 + e] = s;
  }
}

// == k4b: attn-out(dot2 streamed v, FULL unroll) + in_proj + LN2 + ffn_in ====
__global__ __launch_bounds__(256, 3) void k4b(
    char* __restrict__ region, float4* __restrict__ s0arr,
    const float* __restrict__ x, const float* __restrict__ ipw,
    const float* __restrict__ ipb, const float* __restrict__ Mws,
    const float* __restrict__ aob, const float* __restrict__ lnw,
    const float* __restrict__ lnb, const float* __restrict__ fiw,
    const float* __restrict__ fib, const float* __restrict__ opw) {
  __shared__ __align__(16) unsigned int mtp[24 * 48];   // M pairs: [j2][o]
  __shared__ __align__(16) unsigned int wgp2[24 * 192]; // fiw pairs: [c2][pos]
  __shared__ unsigned int ybuf[24 * 256];               // LN2 out pairs [c2][px]
  __shared__ float fb2[192];
  __shared__ float s_aob[48], s_lnw[48], s_lnb[48], s_opw[144];
  __shared__ float s_ipw[144], s_ipb[48];
  const int tid = threadIdx.x;
  const int b = blockIdx.x >> 8;
  const int gy = blockIdx.x & 255;
  const int n = (gy << 8) + tid;
  for (int i = tid; i < 1152; i += 256) {
    const int j2 = i / 48, o = i - j2 * 48;
    mtp[i] = fpack(Mws[b * 2304 + o * 48 + 2 * j2],
                   Mws[b * 2304 + o * 48 + 2 * j2 + 1]);
  }
  for (int i = tid; i < 4608; i += 256) {
    const int c2 = i / 192, pos = i - c2 * 192;
    const int ch = (pos & 1) ? 96 + (pos >> 1) : (pos >> 1);
    wgp2[i] = fpack(fiw[ch * 48 + 2 * c2], fiw[ch * 48 + 2 * c2 + 1]);
  }
  if (tid < 192) {
    const int ch = (tid & 1) ? 96 + (tid >> 1) : (tid >> 1);
    fb2[tid] = fib[ch];
  }
  if (tid < 144) { s_opw[tid] = opw[tid]; s_ipw[tid] = ipw[tid]; }
  if (tid < 48) {
    s_aob[tid] = aob[tid]; s_lnw[tid] = lnw[tid]; s_lnb[tid] = lnb[tid];
    s_ipb[tid] = ipb[tid];
  }
  __syncthreads();
  char* rowp = region + (size_t)((b << 8) + gy) * ROWB + (tid << 4);
  float y[48];
#pragma unroll
  for (int o = 0; o < 48; ++o) y[o] = s_aob[o];
#pragma unroll
  for (int q = 0; q < 6; ++q) {
    F4U u; u.f4 = *(const float4*)(rowp + (18 + q) * 4096);
#pragma unroll
    for (int k = 0; k < 4; ++k) {
      const unsigned int vp = u.u[k];
      const unsigned int* mr = &mtp[(4 * q + k) * 48];
#pragma unroll
      for (int o = 0; o < 48; ++o) y[o] = fdot2u(vp, mr[o], y[o]);
    }
  }
  const float x0 = x[((size_t)b * 3 + 0) * NPIX + n];
  const float x1 = x[((size_t)b * 3 + 1) * NPIX + n];
  const float x2 = x[((size_t)b * 3 + 2) * NPIX + n];
  float mu = 0.f;
#pragma unroll
  for (int c = 0; c < 48; ++c) {
    y[c] += s_ipw[c * 3] * x0 + s_ipw[c * 3 + 1] * x1 + s_ipw[c * 3 + 2] * x2 + s_ipb[c];
    mu += y[c];
  }
  float s0 = 0.f, s1 = 0.f, s2 = 0.f;
#pragma unroll
  for (int c = 0; c < 48; ++c) {
    s0 += s_opw[c] * y[c]; s1 += s_opw[48 + c] * y[c]; s2 += s_opw[96 + c] * y[c];
  }
  float4 s0v; s0v.x = s0; s0v.y = s1; s0v.z = s2; s0v.w = 0.f;
  s0arr[(size_t)b * NPIX + n] = s0v;
  mu *= (1.f / 48.f);
  float var = 0.f;
#pragma unroll
  for (int c = 0; c < 48; ++c) { const float d = y[c] - mu; var += d * d; }
  const float rs2 = rsqrtf(var * (1.f / 48.f) + 1e-6f);
#pragma unroll
  for (int c2 = 0; c2 < 24; ++c2) {
    const float a = (y[2*c2]   - mu) * rs2 * s_lnw[2*c2]   + s_lnb[2*c2];
    const float bb = (y[2*c2+1] - mu) * rs2 * s_lnw[2*c2+1] + s_lnb[2*c2+1];
    ybuf[c2 * 256 + tid] = fpack(a, bb);
  }
  __builtin_amdgcn_sched_barrier(0);   // y[48] dead; do not merge into conv
#pragma unroll 1
  for (int ob = 0; ob < 12; ++ob) {
    const int o0 = ob * 16;
    float acc[16];
#pragma unroll
    for (int j = 0; j < 16; ++j) acc[j] = fb2[o0 + j];
#pragma unroll 4
    for (int c2 = 0; c2 < 24; ++c2) {
      const unsigned int yp = ybuf[c2 * 256 + tid];
      const uint4* wr = (const uint4*)&wgp2[c2 * 192 + o0];
#pragma unroll
      for (int k = 0; k < 4; ++k) {
        const uint4 w = wr[k];
        acc[4*k+0] = fdot2u(yp, w.x, acc[4*k+0]);
        acc[4*k+1] = fdot2u(yp, w.y, acc[4*k+1]);
        acc[4*k+2] = fdot2u(yp, w.z, acc[4*k+2]);
        acc[4*k+3] = fdot2u(yp, w.w, acc[4*k+3]);
      }
    }
    F4U u;
    u.u[0] = fpack(acc[0], acc[1]);   u.u[1] = fpack(acc[2], acc[3]);
    u.u[2] = fpack(acc[4], acc[5]);   u.u[3] = fpack(acc[6], acc[7]);
    *(float4*)(rowp + (2 * ob) * 4096) = u.f4;
    u.u[0] = fpack(acc[8], acc[9]);   u.u[1] = fpack(acc[10], acc[11]);
    u.u[2] = fpack(acc[12], acc[13]); u.u[3] = fpack(acc[14], acc[15]);
    *(float4*)(rowp + (2 * ob + 1) * 4096) = u.f4;
    __builtin_amdgcn_sched_barrier(0);
  }
}

// ====== k5b: dw(pk_fma) + SimpleGate + ffn_out + out_proj ===================
__global__ __launch_bounds__(256, 2) void k5b(
    const char* __restrict__ region, const float4* __restrict__ s0arr,
    const float* __restrict__ fdww, const float* __restrict__ fdwb,
    const float* __restrict__ fow, const float* __restrict__ fob,
    const float* __restrict__ opw, const float* __restrict__ opb,
    float* __restrict__ out) {
  __shared__ unsigned int halo[12 * HSTRIDE];
  __shared__ __align__(16) float fowT[96 * 48];   // fowT[c1][o] = fow[o][c1]
  __shared__ unsigned int dwp2[96 * 9];           // packed (w[a][t], w[96+a][t])
  __shared__ unsigned int dbp2[96];               // packed (b[a], b[96+a])
  __shared__ float s_opw[144], s_fob[48];
  const int tid = threadIdx.x;
  for (int i = tid; i < 4608; i += 256) {
    const int c = i / 48, o = i - c * 48;
    fowT[i] = fow[o * 96 + c];
  }
  for (int i = tid; i < 864; i += 256) {
    const int a = i / 9, t = i - a * 9;
    dwp2[i] = fpack(fdww[a * 9 + t], fdww[(96 + a) * 9 + t]);
  }
  if (tid < 96) dbp2[tid] = fpack(fdwb[tid], fdwb[96 + tid]);
  if (tid < 144) s_opw[tid] = opw[tid];
  if (tid < 48) s_fob[tid] = fob[tid];
  const int b = blockIdx.x >> 8;
  const int tile = blockIdx.x & 255;
  const int ty0 = (tile >> 4) << 4, tx0 = (tile & 15) << 4;
  const int py = tid >> 4, px = tid & 15;
  const int hp = (py + 1) * 18 + (px + 1);
  const int gn = ((ty0 + py) << 8) + (tx0 + px);
  const char* regb = region + (size_t)b * REGPB;

  float4 pf[4];
  auto prefetch = [&](int cb) {
#pragma unroll
    for (int r = 0; r < 4; ++r) {
      const int i = tid + (r << 8);
      float4 z = {0.f, 0.f, 0.f, 0.f}; pf[r] = z;
      if (i < 972) {
        const int c4 = i / 324, p = i - c4 * 324;
        const int hy = p / 18, hx = p - hy * 18;
        const int gy = ty0 + hy - 1, gx = tx0 + hx - 1;
        if (((unsigned)gy < 256u) && ((unsigned)gx < 256u))
          pf[r] = *(const float4*)(regb + (size_t)gy * ROWB + (cb + c4) * 4096 + (gx << 4));
      }
    }
  };
  auto commit = [&]() {
#pragma unroll
    for (int r = 0; r < 4; ++r) {
      const int i = tid + (r << 8);
      if (i < 972) {
        const int c4 = i / 324, p = i - c4 * 324;
        F4U u; u.f4 = pf[r];
        const int pb = c4 << 2;
#pragma unroll
        for (int j = 0; j < 4; ++j) halo[(pb + j) * HSTRIDE + p] = u.u[j];
      }
    }
  };

  float facc[48];
#pragma unroll
  for (int o = 0; o < 48; ++o) facc[o] = 0.f;
  prefetch(0);
  for (int s = 0; s < 8; ++s) {
    __syncthreads(); commit(); __syncthreads();
    if (s < 7) prefetch(3 * (s + 1));
    const int offs[9] = {-19, -18, -17, -1, 0, 1, 17, 18, 19};
#pragma unroll
    for (int pp = 0; pp < 12; ++pp) {
      const int a = 12 * s + pp;            // gate pair (ch a, ch 96+a)
      U32H2 acc; acc.u = dbp2[a];
      const unsigned int* hrow = &halo[pp * HSTRIDE + hp];
      const unsigned int* wp = &dwp2[a * 9];
#pragma unroll
      for (int t = 0; t < 9; ++t) {
        U32H2 f, w; f.u = hrow[offs[t]]; w.u = wp[t];
        acc.h = w.h * f.h + acc.h;          // v_pk_fma_f16
      }
      const float2 ab = uh2f(acc.u);
      const float gate = ab.x * ab.y;
      const float* fr = &fowT[a * 48];
#pragma unroll
      for (int o4 = 0; o4 < 12; ++o4) {
        const float4 m = *(const float4*)&fr[o4 * 4];
        facc[o4 * 4 + 0] += m.x * gate; facc[o4 * 4 + 1] += m.y * gate;
        facc[o4 * 4 + 2] += m.z * gate; facc[o4 * 4 + 3] += m.w * gate;
      }
    }
  }
  const float4 s0v = s0arr[(size_t)b * NPIX + gn];
  float r0 = s0v.x + opb[0];
  float r1 = s0v.y + opb[1];
  float r2 = s0v.z + opb[2];
#pragma unroll
  for (int o = 0; o < 48; ++o) {
    const float f = facc[o] + s_fob[o];
    r0 += s_opw[o] * f; r1 += s_opw[48 + o] * f; r2 += s_opw[96 + o] * f;
  }
  out[((size_t)b * 3 + 0) * NPIX + gn] = r0;
  out[((size_t)b * 3 + 1) * NPIX + gn] = r1;
  out[((size_t)b * 3 + 2) * NPIX + gn] = r2;
}

extern "C" void kernel_launch(void* const* d_in, const int* in_sizes, int n_in,
                              void* d_out, int out_size, void* d_ws, size_t ws_size,
                              hipStream_t stream) {
  const float* x    = (const float*)d_in[0];
  const float* ipw  = (const float*)d_in[1];
  const float* ipb  = (const float*)d_in[2];
  const float* ln1w = (const float*)d_in[3];
  const float* ln1b = (const float*)d_in[4];
  const float* qw   = (const float*)d_in[5];
  const float* qb   = (const float*)d_in[6];
  const float* qdww = (const float*)d_in[7];
  const float* qdwb = (const float*)d_in[8];
  const float* temp = (const float*)d_in[9];
  const float* aow  = (const float*)d_in[10];
  const float* aob  = (const float*)d_in[11];
  const float* ln2w = (const float*)d_in[12];
  const float* ln2b = (const float*)d_in[13];
  const float* fiw  = (const float*)d_in[14];
  const float* fib  = (const float*)d_in[15];
  const float* fdww = (const float*)d_in[16];
  const float* fdwb = (const float*)d_in[17];
  const float* fow  = (const float*)d_in[18];
  const float* fob  = (const float*)d_in[19];
  const float* opw  = (const float*)d_in[20];
  const float* opb  = (const float*)d_in[21];

  const size_t s0Per = (size_t)NPIX * 16;
  int bc = 8;
  while (bc > 1 &&
         (size_t)bc * (REGPB + s0Per) + (5376 + 18432) * 4 > ws_size)
    bc >>= 1;
  char* region = (char*)d_ws;
  float4* s0arr = (float4*)(region + (size_t)bc * REGPB);
  float* red = (float*)((char*)s0arr + (size_t)bc * s0Per);
  float* Mws = red + 5376;
  hipMemsetAsync(red, 0, 5376 * sizeof(float), stream);
  for (int b0 = 0; b0 < 8; b0 += bc) {
    kA9<<<bc * 256, 256, 0, stream>>>(x + (size_t)b0 * 3 * NPIX, ipw, ipb,
                                      ln1w, ln1b, qw, qb, qdww, qdwb,
                                      region, red + b0 * 672);
    k3_attn<<<bc, 256, 0, stream>>>(red + b0 * 672, temp, aow,
                                    Mws + (size_t)b0 * 2304);
    k4b<<<bc * 256, 256, 0, stream>>>(region, s0arr, x + (size_t)b0 * 3 * NPIX,
                                      ipw, ipb, Mws + (size_t)b0 * 2304, aob,
                                      ln2w, ln2b, fiw, fib, opw);
    k5b<<<bc * 256, 256, 0, stream>>>(region, s0arr, fdww, fdwb, fow, fob,
                                      opw, opb,
                                      (float*)d_out + (size_t)b0 * 3 * NPIX);
  }
}